// Round 1
// baseline (838.291 us; speedup 1.0000x reference)
//
#include <hip/hip_runtime.h>
#include <hip/hip_bf16.h>
#include <math.h>

// ---------------------------------------------------------------------------
// SelfAttention2d: x(8,256,32,32) -> GN(8 groups) -> qkv(768x256 GEMM)
//   -> 32 heads, d=8, attention over t=1024 -> out(256x256 GEMM) + bias + x
// Round 1: correct fp32 baseline. 4 kernels, ws = xn | qkv | y.
// ---------------------------------------------------------------------------

#define NBATCH 8
#define C 256
#define HW 1024
#define NHEAD 32
#define HDIM 8

// ---------------- GroupNorm: 64 blocks (n*8+g), 256 threads -----------------
__global__ __launch_bounds__(256) void gn_kernel(
    const float* __restrict__ x, const float* __restrict__ w,
    const float* __restrict__ b, float* __restrict__ xn)
{
    int n = blockIdx.x >> 3, g = blockIdx.x & 7;
    const float* xp = x + ((size_t)n * C + g * 32) * HW;
    float* op = xn + ((size_t)n * C + g * 32) * HW;
    int tid = threadIdx.x;
    const float4* xv = (const float4*)xp;
    float s = 0.f, ss = 0.f;
    for (int i = tid; i < 8192; i += 256) {
        float4 v = xv[i];
        s  += v.x + v.y + v.z + v.w;
        ss += v.x*v.x + v.y*v.y + v.z*v.z + v.w*v.w;
    }
#pragma unroll
    for (int o = 32; o; o >>= 1) { s += __shfl_xor(s, o); ss += __shfl_xor(ss, o); }
    __shared__ float rs[4], rss[4];
    int wave = tid >> 6, lane = tid & 63;
    if (lane == 0) { rs[wave] = s; rss[wave] = ss; }
    __syncthreads();
    s  = rs[0] + rs[1] + rs[2] + rs[3];
    ss = rss[0] + rss[1] + rss[2] + rss[3];
    const float invN = 1.0f / 32768.0f;
    float mean = s * invN;
    float var  = ss * invN - mean * mean;
    float rstd = rsqrtf(var + 1e-5f);
    float4* ov = (float4*)op;
    for (int i = tid; i < 8192; i += 256) {
        int c = g * 32 + (i >> 8);           // 256 float4 per channel
        float wc = w[c] * rstd;
        float bc = b[c] - mean * wc;
        float4 v = xv[i];
        float4 o4;
        o4.x = v.x * wc + bc; o4.y = v.y * wc + bc;
        o4.z = v.z * wc + bc; o4.w = v.w * wc + bc;
        ov[i] = o4;
    }
}

// ------------- fp32 GEMM: C[n] = A(Mx256) * B[n](256x1024) + bias -----------
// 64x64 tile, BK=16, 256 threads, 4x4 micro. Optional residual add.
__global__ __launch_bounds__(256) void gemm_bias_kernel(
    const float* __restrict__ A, const float* __restrict__ Ball,
    const float* __restrict__ bias, float* __restrict__ Call,
    const float* __restrict__ Rall, int M)
{
    int n = blockIdx.z;
    const float* B = Ball + (size_t)n * C * HW;
    float* Cp = Call + (size_t)n * M * HW;
    const float* R = Rall ? Rall + (size_t)n * M * HW : nullptr;
    int om0 = blockIdx.y * 64;
    int t0  = blockIdx.x * 64;
    __shared__ float As[16][64];
    __shared__ float Bs[16][64];
    int tid = threadIdx.x;
    int ty = tid >> 4, tx = tid & 15;
    int arow = tid >> 2, acol = (tid & 3) * 4;
    int brow = tid >> 4, bcol = (tid & 15) * 4;
    float acc[4][4] = {};
    for (int c0 = 0; c0 < C; c0 += 16) {
        float4 av = *(const float4*)&A[(size_t)(om0 + arow) * C + c0 + acol];
        float4 bv = *(const float4*)&B[(size_t)(c0 + brow) * HW + t0 + bcol];
        As[acol + 0][arow] = av.x; As[acol + 1][arow] = av.y;
        As[acol + 2][arow] = av.z; As[acol + 3][arow] = av.w;
        *(float4*)&Bs[brow][bcol] = bv;
        __syncthreads();
#pragma unroll
        for (int kk = 0; kk < 16; ++kk) {
            const float4 a = *(const float4*)&As[kk][ty * 4];
            const float4 bb = *(const float4*)&Bs[kk][tx * 4];
            const float ar[4] = {a.x, a.y, a.z, a.w};
            const float br[4] = {bb.x, bb.y, bb.z, bb.w};
#pragma unroll
            for (int i = 0; i < 4; ++i)
#pragma unroll
                for (int j = 0; j < 4; ++j)
                    acc[i][j] = fmaf(ar[i], br[j], acc[i][j]);
        }
        __syncthreads();
    }
#pragma unroll
    for (int i = 0; i < 4; ++i) {
        int row = om0 + ty * 4 + i;
        float bb = bias[row];
        float4 o;
        o.x = acc[i][0] + bb; o.y = acc[i][1] + bb;
        o.z = acc[i][2] + bb; o.w = acc[i][3] + bb;
        if (R) {
            float4 rv = *(const float4*)&R[(size_t)row * HW + t0 + tx * 4];
            o.x += rv.x; o.y += rv.y; o.z += rv.z; o.w += rv.w;
        }
        *(float4*)&Cp[(size_t)row * HW + t0 + tx * 4] = o;
    }
}

// -------- attention: 512 blocks = (head, half of rows), 256 threads ---------
// K,V for one head staged in LDS [d][t] (stride-1 lane reads, conflict-free).
// Each wave processes 4 query rows per iter; scores kept in regs; two-pass
// softmax (max reduce, then exp+accumulate), butterfly reductions.
__global__ __launch_bounds__(256) void attn_kernel(
    const float* __restrict__ qkv, float* __restrict__ y)
{
    int bh = blockIdx.x >> 1;
    int half = blockIdx.x & 1;
    int n = bh >> 5, h = bh & 31;
    __shared__ float Ks[HDIM][HW];
    __shared__ float Vs[HDIM][HW];
    const float* base = qkv + (size_t)n * 3 * C * HW;
    const float* qp = base + (size_t)(h * HDIM) * HW;
    const float* kp = base + (size_t)(C + h * HDIM) * HW;
    const float* vp = base + (size_t)(2 * C + h * HDIM) * HW;
    int tid = threadIdx.x;
    const float4* k4 = (const float4*)kp;
    const float4* v4 = (const float4*)vp;
    float4* Ks4 = (float4*)Ks;
    float4* Vs4 = (float4*)Vs;
    for (int i = tid; i < 2048; i += 256) { Ks4[i] = k4[i]; Vs4[i] = v4[i]; }
    __syncthreads();
    int wave = tid >> 6, lane = tid & 63;
    const float scale = 0.3535533905932738f;  // 1/sqrt(8)
    for (int it = 0; it < 32; ++it) {
        int r0 = half * 512 + (it * 4 + wave) * 4;
        float q[4][8];
#pragma unroll
        for (int r = 0; r < 4; ++r)
#pragma unroll
            for (int d = 0; d < 8; ++d)
                q[r][d] = qp[(size_t)d * HW + r0 + r];
        float m[4] = {-1e30f, -1e30f, -1e30f, -1e30f};
        float sc[4][16];
#pragma unroll
        for (int kk = 0; kk < 16; ++kk) {
            int t = kk * 64 + lane;
            float kv[8];
#pragma unroll
            for (int d = 0; d < 8; ++d) kv[d] = Ks[d][t];
#pragma unroll
            for (int r = 0; r < 4; ++r) {
                float s2 = 0.f;
#pragma unroll
                for (int d = 0; d < 8; ++d) s2 = fmaf(q[r][d], kv[d], s2);
                s2 *= scale;
                sc[r][kk] = s2;
                m[r] = fmaxf(m[r], s2);
            }
        }
#pragma unroll
        for (int r = 0; r < 4; ++r)
#pragma unroll
            for (int o = 32; o; o >>= 1)
                m[r] = fmaxf(m[r], __shfl_xor(m[r], o));
        float l[4] = {0.f, 0.f, 0.f, 0.f};
        float acc[4][8] = {};
#pragma unroll
        for (int kk = 0; kk < 16; ++kk) {
            int t = kk * 64 + lane;
            float vv[8];
#pragma unroll
            for (int d = 0; d < 8; ++d) vv[d] = Vs[d][t];
#pragma unroll
            for (int r = 0; r < 4; ++r) {
                float p = __expf(sc[r][kk] - m[r]);
                l[r] += p;
#pragma unroll
                for (int d = 0; d < 8; ++d)
                    acc[r][d] = fmaf(p, vv[d], acc[r][d]);
            }
        }
#pragma unroll
        for (int o = 32; o; o >>= 1) {
#pragma unroll
            for (int r = 0; r < 4; ++r) {
                l[r] += __shfl_xor(l[r], o);
#pragma unroll
                for (int d = 0; d < 8; ++d)
                    acc[r][d] += __shfl_xor(acc[r][d], o);
            }
        }
        if (lane == 0) {
#pragma unroll
            for (int r = 0; r < 4; ++r) {
                float inv = 1.0f / l[r];
#pragma unroll
                for (int d = 0; d < 8; ++d)
                    y[((size_t)n * C + h * HDIM + d) * HW + r0 + r] = acc[r][d] * inv;
            }
        }
    }
}

// ---------------------------------------------------------------------------
extern "C" void kernel_launch(void* const* d_in, const int* in_sizes, int n_in,
                              void* d_out, int out_size, void* d_ws, size_t ws_size,
                              hipStream_t stream)
{
    const float* x     = (const float*)d_in[0];
    const float* gn_w  = (const float*)d_in[1];
    const float* gn_b  = (const float*)d_in[2];
    const float* qkv_w = (const float*)d_in[3];
    const float* qkv_b = (const float*)d_in[4];
    const float* out_w = (const float*)d_in[5];
    const float* out_b = (const float*)d_in[6];
    float* out = (float*)d_out;

    float* xn  = (float*)d_ws;                       // 8*256*1024
    float* qkv = xn + (size_t)NBATCH * C * HW;       // 8*768*1024
    float* y   = xn + (size_t)4 * NBATCH * C * HW;   // 8*256*1024

    gn_kernel<<<64, 256, 0, stream>>>(x, gn_w, gn_b, xn);
    gemm_bias_kernel<<<dim3(16, 12, 8), 256, 0, stream>>>(qkv_w, xn, qkv_b, qkv,
                                                          nullptr, 3 * C);
    attn_kernel<<<512, 256, 0, stream>>>(qkv, y);
    gemm_bias_kernel<<<dim3(16, 4, 8), 256, 0, stream>>>(out_w, y, out_b, out,
                                                         x, C);
}

// Round 2
// 717.272 us; speedup vs baseline: 1.1687x; 1.1687x over previous
//
#include <hip/hip_runtime.h>
#include <hip/hip_bf16.h>
#include <math.h>

// ---------------------------------------------------------------------------
// SelfAttention2d: x(8,256,32,32) -> GN(8 groups) -> qkv(768x256 GEMM)
//   -> 32 heads, d=8, attention over t=1024 -> out(256x256 GEMM) + bias + x
// Round 2: fused single-pass attention, no-max online softmax, no spill.
// ---------------------------------------------------------------------------

#define NBATCH 8
#define C 256
#define HW 1024
#define NHEAD 32
#define HDIM 8

// ---------------- GroupNorm: 64 blocks (n*8+g), 256 threads -----------------
__global__ __launch_bounds__(256) void gn_kernel(
    const float* __restrict__ x, const float* __restrict__ w,
    const float* __restrict__ b, float* __restrict__ xn)
{
    int n = blockIdx.x >> 3, g = blockIdx.x & 7;
    const float* xp = x + ((size_t)n * C + g * 32) * HW;
    float* op = xn + ((size_t)n * C + g * 32) * HW;
    int tid = threadIdx.x;
    const float4* xv = (const float4*)xp;
    float s = 0.f, ss = 0.f;
    for (int i = tid; i < 8192; i += 256) {
        float4 v = xv[i];
        s  += v.x + v.y + v.z + v.w;
        ss += v.x*v.x + v.y*v.y + v.z*v.z + v.w*v.w;
    }
#pragma unroll
    for (int o = 32; o; o >>= 1) { s += __shfl_xor(s, o); ss += __shfl_xor(ss, o); }
    __shared__ float rs[4], rss[4];
    int wave = tid >> 6, lane = tid & 63;
    if (lane == 0) { rs[wave] = s; rss[wave] = ss; }
    __syncthreads();
    s  = rs[0] + rs[1] + rs[2] + rs[3];
    ss = rss[0] + rss[1] + rss[2] + rss[3];
    const float invN = 1.0f / 32768.0f;
    float mean = s * invN;
    float var  = ss * invN - mean * mean;
    float rstd = rsqrtf(var + 1e-5f);
    float4* ov = (float4*)op;
    for (int i = tid; i < 8192; i += 256) {
        int c = g * 32 + (i >> 8);           // 256 float4 per channel
        float wc = w[c] * rstd;
        float bc = b[c] - mean * wc;
        float4 v = xv[i];
        float4 o4;
        o4.x = v.x * wc + bc; o4.y = v.y * wc + bc;
        o4.z = v.z * wc + bc; o4.w = v.w * wc + bc;
        ov[i] = o4;
    }
}

// ------------- fp32 GEMM: C[n] = A(Mx256) * B[n](256x1024) + bias -----------
// 64x64 tile, BK=16, 256 threads, 4x4 micro. Optional residual add.
__global__ __launch_bounds__(256) void gemm_bias_kernel(
    const float* __restrict__ A, const float* __restrict__ Ball,
    const float* __restrict__ bias, float* __restrict__ Call,
    const float* __restrict__ Rall, int M)
{
    int n = blockIdx.z;
    const float* B = Ball + (size_t)n * C * HW;
    float* Cp = Call + (size_t)n * M * HW;
    const float* R = Rall ? Rall + (size_t)n * M * HW : nullptr;
    int om0 = blockIdx.y * 64;
    int t0  = blockIdx.x * 64;
    __shared__ float As[16][64];
    __shared__ float Bs[16][64];
    int tid = threadIdx.x;
    int ty = tid >> 4, tx = tid & 15;
    int arow = tid >> 2, acol = (tid & 3) * 4;
    int brow = tid >> 4, bcol = (tid & 15) * 4;
    float acc[4][4] = {};
    for (int c0 = 0; c0 < C; c0 += 16) {
        float4 av = *(const float4*)&A[(size_t)(om0 + arow) * C + c0 + acol];
        float4 bv = *(const float4*)&B[(size_t)(c0 + brow) * HW + t0 + bcol];
        As[acol + 0][arow] = av.x; As[acol + 1][arow] = av.y;
        As[acol + 2][arow] = av.z; As[acol + 3][arow] = av.w;
        *(float4*)&Bs[brow][bcol] = bv;
        __syncthreads();
#pragma unroll
        for (int kk = 0; kk < 16; ++kk) {
            const float4 a = *(const float4*)&As[kk][ty * 4];
            const float4 bb = *(const float4*)&Bs[kk][tx * 4];
            const float ar[4] = {a.x, a.y, a.z, a.w};
            const float br[4] = {bb.x, bb.y, bb.z, bb.w};
#pragma unroll
            for (int i = 0; i < 4; ++i)
#pragma unroll
                for (int j = 0; j < 4; ++j)
                    acc[i][j] = fmaf(ar[i], br[j], acc[i][j]);
        }
        __syncthreads();
    }
#pragma unroll
    for (int i = 0; i < 4; ++i) {
        int row = om0 + ty * 4 + i;
        float bb = bias[row];
        float4 o;
        o.x = acc[i][0] + bb; o.y = acc[i][1] + bb;
        o.z = acc[i][2] + bb; o.w = acc[i][3] + bb;
        if (R) {
            float4 rv = *(const float4*)&R[(size_t)row * HW + t0 + tx * 4];
            o.x += rv.x; o.y += rv.y; o.z += rv.z; o.w += rv.w;
        }
        *(float4*)&Cp[(size_t)row * HW + t0 + tx * 4] = o;
    }
}

// -------- attention: 512 blocks = (n,h, half of rows), 256 threads ----------
// K,V for one head staged fp32 in LDS [d][t] (stride-1 lane reads, 2-way free).
// Single fused pass: no-max softmax (|s| << 87 for O(1)-variance inputs, so
// exp() cannot overflow fp32; +1e-30 on l guards the all-underflow corner).
// Each wave: 4 query rows/iter; per-lane online accumulation over its 16
// t-positions; one 64-lane butterfly reduction per 4-row tile.
// State/lane: q[4][8] (scale folded) + acc[4][8] + l[4] + k/v temps ~= 106 VGPR.
__global__ __launch_bounds__(256) void attn_kernel(
    const float* __restrict__ qkv, float* __restrict__ y)
{
    int bh = blockIdx.x >> 1;
    int half = blockIdx.x & 1;
    int n = bh >> 5, h = bh & 31;
    __shared__ float Ks[HDIM][HW];
    __shared__ float Vs[HDIM][HW];
    const float* base = qkv + (size_t)n * 3 * C * HW;
    const float* qp = base + (size_t)(h * HDIM) * HW;
    const float* kp = base + (size_t)(C + h * HDIM) * HW;
    const float* vp = base + (size_t)(2 * C + h * HDIM) * HW;
    int tid = threadIdx.x;
    const float4* k4 = (const float4*)kp;
    const float4* v4 = (const float4*)vp;
    float4* Ks4 = (float4*)Ks;
    float4* Vs4 = (float4*)Vs;
    for (int i = tid; i < 2048; i += 256) { Ks4[i] = k4[i]; Vs4[i] = v4[i]; }
    __syncthreads();
    int wave = tid >> 6, lane = tid & 63;
    const float scale = 0.3535533905932738f;  // 1/sqrt(8)
    for (int it = 0; it < 32; ++it) {
        int r0 = half * 512 + (it * 4 + wave) * 4;
        float q[4][8];
#pragma unroll
        for (int r = 0; r < 4; ++r)
#pragma unroll
            for (int d = 0; d < 8; ++d)
                q[r][d] = qp[(size_t)d * HW + r0 + r] * scale;
        float l[4] = {0.f, 0.f, 0.f, 0.f};
        float acc[4][8] = {};
#pragma unroll
        for (int kk = 0; kk < 16; ++kk) {
            int t = kk * 64 + lane;
            float kv[8], vv[8];
#pragma unroll
            for (int d = 0; d < 8; ++d) kv[d] = Ks[d][t];
#pragma unroll
            for (int d = 0; d < 8; ++d) vv[d] = Vs[d][t];
#pragma unroll
            for (int r = 0; r < 4; ++r) {
                float s2 = 0.f;
#pragma unroll
                for (int d = 0; d < 8; ++d) s2 = fmaf(q[r][d], kv[d], s2);
                float p = __expf(s2);
                l[r] += p;
#pragma unroll
                for (int d = 0; d < 8; ++d)
                    acc[r][d] = fmaf(p, vv[d], acc[r][d]);
            }
        }
#pragma unroll
        for (int o = 32; o; o >>= 1) {
#pragma unroll
            for (int r = 0; r < 4; ++r) {
                l[r] += __shfl_xor(l[r], o);
#pragma unroll
                for (int d = 0; d < 8; ++d)
                    acc[r][d] += __shfl_xor(acc[r][d], o);
            }
        }
#pragma unroll
        for (int r = 0; r < 4; ++r) {
            if (lane == r) {                      // compile-time reg indices
                float inv = 1.0f / (l[r] + 1e-30f);
#pragma unroll
                for (int d = 0; d < 8; ++d)
                    y[((size_t)n * C + h * HDIM + d) * HW + r0 + r] = acc[r][d] * inv;
            }
        }
    }
}

// ---------------------------------------------------------------------------
extern "C" void kernel_launch(void* const* d_in, const int* in_sizes, int n_in,
                              void* d_out, int out_size, void* d_ws, size_t ws_size,
                              hipStream_t stream)
{
    const float* x     = (const float*)d_in[0];
    const float* gn_w  = (const float*)d_in[1];
    const float* gn_b  = (const float*)d_in[2];
    const float* qkv_w = (const float*)d_in[3];
    const float* qkv_b = (const float*)d_in[4];
    const float* out_w = (const float*)d_in[5];
    const float* out_b = (const float*)d_in[6];
    float* out = (float*)d_out;

    float* xn  = (float*)d_ws;                       // 8*256*1024
    float* qkv = xn + (size_t)NBATCH * C * HW;       // 8*768*1024
    float* y   = xn + (size_t)4 * NBATCH * C * HW;   // 8*256*1024

    gn_kernel<<<64, 256, 0, stream>>>(x, gn_w, gn_b, xn);
    gemm_bias_kernel<<<dim3(16, 12, 8), 256, 0, stream>>>(qkv_w, xn, qkv_b, qkv,
                                                          nullptr, 3 * C);
    attn_kernel<<<512, 256, 0, stream>>>(qkv, y);
    gemm_bias_kernel<<<dim3(16, 4, 8), 256, 0, stream>>>(out_w, y, out_b, out,
                                                         x, C);
}

// Round 3
// 309.085 us; speedup vs baseline: 2.7122x; 2.3206x over previous
//
#include <hip/hip_runtime.h>
#include <hip/hip_bf16.h>
#include <math.h>

// ---------------------------------------------------------------------------
// SelfAttention2d: x(8,256,32,32) -> GN(8 groups) -> qkv(768x256 GEMM)
//   -> 32 heads, d=8, attention over t=1024 -> out(256x256 GEMM) + bias + x
// Round 3: row-per-lane attention. One query row per lane (x2), K/V staged
// t-major in LDS and read as wave-uniform broadcasts. No shuffles/reductions.
// ---------------------------------------------------------------------------

#define NBATCH 8
#define C 256
#define HW 1024
#define NHEAD 32
#define HDIM 8

// ---------------- GroupNorm: 64 blocks (n*8+g), 256 threads -----------------
__global__ __launch_bounds__(256) void gn_kernel(
    const float* __restrict__ x, const float* __restrict__ w,
    const float* __restrict__ b, float* __restrict__ xn)
{
    int n = blockIdx.x >> 3, g = blockIdx.x & 7;
    const float* xp = x + ((size_t)n * C + g * 32) * HW;
    float* op = xn + ((size_t)n * C + g * 32) * HW;
    int tid = threadIdx.x;
    const float4* xv = (const float4*)xp;
    float s = 0.f, ss = 0.f;
    for (int i = tid; i < 8192; i += 256) {
        float4 v = xv[i];
        s  += v.x + v.y + v.z + v.w;
        ss += v.x*v.x + v.y*v.y + v.z*v.z + v.w*v.w;
    }
#pragma unroll
    for (int o = 32; o; o >>= 1) { s += __shfl_xor(s, o); ss += __shfl_xor(ss, o); }
    __shared__ float rs[4], rss[4];
    int wave = tid >> 6, lane = tid & 63;
    if (lane == 0) { rs[wave] = s; rss[wave] = ss; }
    __syncthreads();
    s  = rs[0] + rs[1] + rs[2] + rs[3];
    ss = rss[0] + rss[1] + rss[2] + rss[3];
    const float invN = 1.0f / 32768.0f;
    float mean = s * invN;
    float var  = ss * invN - mean * mean;
    float rstd = rsqrtf(var + 1e-5f);
    float4* ov = (float4*)op;
    for (int i = tid; i < 8192; i += 256) {
        int c = g * 32 + (i >> 8);           // 256 float4 per channel
        float wc = w[c] * rstd;
        float bc = b[c] - mean * wc;
        float4 v = xv[i];
        float4 o4;
        o4.x = v.x * wc + bc; o4.y = v.y * wc + bc;
        o4.z = v.z * wc + bc; o4.w = v.w * wc + bc;
        ov[i] = o4;
    }
}

// ------------- fp32 GEMM: C[n] = A(Mx256) * B[n](256x1024) + bias -----------
// 64x64 tile, BK=16, 256 threads, 4x4 micro. Optional residual add.
__global__ __launch_bounds__(256) void gemm_bias_kernel(
    const float* __restrict__ A, const float* __restrict__ Ball,
    const float* __restrict__ bias, float* __restrict__ Call,
    const float* __restrict__ Rall, int M)
{
    int n = blockIdx.z;
    const float* B = Ball + (size_t)n * C * HW;
    float* Cp = Call + (size_t)n * M * HW;
    const float* R = Rall ? Rall + (size_t)n * M * HW : nullptr;
    int om0 = blockIdx.y * 64;
    int t0  = blockIdx.x * 64;
    __shared__ float As[16][64];
    __shared__ float Bs[16][64];
    int tid = threadIdx.x;
    int ty = tid >> 4, tx = tid & 15;
    int arow = tid >> 2, acol = (tid & 3) * 4;
    int brow = tid >> 4, bcol = (tid & 15) * 4;
    float acc[4][4] = {};
    for (int c0 = 0; c0 < C; c0 += 16) {
        float4 av = *(const float4*)&A[(size_t)(om0 + arow) * C + c0 + acol];
        float4 bv = *(const float4*)&B[(size_t)(c0 + brow) * HW + t0 + bcol];
        As[acol + 0][arow] = av.x; As[acol + 1][arow] = av.y;
        As[acol + 2][arow] = av.z; As[acol + 3][arow] = av.w;
        *(float4*)&Bs[brow][bcol] = bv;
        __syncthreads();
#pragma unroll
        for (int kk = 0; kk < 16; ++kk) {
            const float4 a = *(const float4*)&As[kk][ty * 4];
            const float4 bb = *(const float4*)&Bs[kk][tx * 4];
            const float ar[4] = {a.x, a.y, a.z, a.w};
            const float br[4] = {bb.x, bb.y, bb.z, bb.w};
#pragma unroll
            for (int i = 0; i < 4; ++i)
#pragma unroll
                for (int j = 0; j < 4; ++j)
                    acc[i][j] = fmaf(ar[i], br[j], acc[i][j]);
        }
        __syncthreads();
    }
#pragma unroll
    for (int i = 0; i < 4; ++i) {
        int row = om0 + ty * 4 + i;
        float bb = bias[row];
        float4 o;
        o.x = acc[i][0] + bb; o.y = acc[i][1] + bb;
        o.z = acc[i][2] + bb; o.w = acc[i][3] + bb;
        if (R) {
            float4 rv = *(const float4*)&R[(size_t)row * HW + t0 + tx * 4];
            o.x += rv.x; o.y += rv.y; o.z += rv.z; o.w += rv.w;
        }
        *(float4*)&Cp[(size_t)row * HW + t0 + tx * 4] = o;
    }
}

// -------- attention: 512 blocks = (n,h,half), 256 threads, 2 rows/lane ------
// K,V staged fp32 in LDS t-major [t][8]; per-t reads are wave-uniform
// broadcasts (2x ds_read_b128 each) -> conflict-free, 4 DS instr per t.
// Softmax is lane-private (no-max: |s|<<87 for O(1)-variance inputs; exp2
// with scale*log2e folded into q). No cross-lane reductions anywhere.
__global__ __launch_bounds__(256, 4) void attn_kernel(
    const float* __restrict__ qkv, float* __restrict__ y)
{
    int bh = blockIdx.x >> 1;
    int half = blockIdx.x & 1;
    int n = bh >> 5, h = bh & 31;
    __shared__ float Ks[HW][HDIM];   // 32 KB
    __shared__ float Vs[HW][HDIM];   // 32 KB
    const float* base = qkv + (size_t)n * 3 * C * HW;
    const float* qp = base + (size_t)(h * HDIM) * HW;
    const float* kp = base + (size_t)(C + h * HDIM) * HW;
    const float* vp = base + (size_t)(2 * C + h * HDIM) * HW;
    int tid = threadIdx.x;
    // stage K,V transposed: for fixed d, lanes read consecutive t (coalesced)
    for (int t = tid; t < HW; t += 256) {
        float kv[8], vv[8];
#pragma unroll
        for (int d = 0; d < 8; ++d) kv[d] = kp[(size_t)d * HW + t];
#pragma unroll
        for (int d = 0; d < 8; ++d) vv[d] = vp[(size_t)d * HW + t];
        *(float4*)&Ks[t][0] = make_float4(kv[0], kv[1], kv[2], kv[3]);
        *(float4*)&Ks[t][4] = make_float4(kv[4], kv[5], kv[6], kv[7]);
        *(float4*)&Vs[t][0] = make_float4(vv[0], vv[1], vv[2], vv[3]);
        *(float4*)&Vs[t][4] = make_float4(vv[4], vv[5], vv[6], vv[7]);
    }
    __syncthreads();
    int wave = tid >> 6, lane = tid & 63;
    int r0 = half * 512 + wave * 128 + lane;   // row 0 of this lane
    int r1 = r0 + 64;                          // row 1
    // fold scale * log2(e) into q so p = exp2(s) maps to native v_exp_f32
    const float sl = 0.3535533905932738f * 1.4426950408889634f;
    float q0[8], q1[8];
#pragma unroll
    for (int d = 0; d < 8; ++d) q0[d] = qp[(size_t)d * HW + r0] * sl;
#pragma unroll
    for (int d = 0; d < 8; ++d) q1[d] = qp[(size_t)d * HW + r1] * sl;
    float l0 = 0.f, l1 = 0.f;
    float a0[8] = {}, a1[8] = {};
#pragma unroll 2
    for (int t = 0; t < HW; ++t) {
        float4 ka = *(const float4*)&Ks[t][0];
        float4 kb = *(const float4*)&Ks[t][4];
        // two half-chains per row for ILP
        float s0a = q0[0] * ka.x, s0b = q0[4] * kb.x;
        s0a = fmaf(q0[1], ka.y, s0a); s0b = fmaf(q0[5], kb.y, s0b);
        s0a = fmaf(q0[2], ka.z, s0a); s0b = fmaf(q0[6], kb.z, s0b);
        s0a = fmaf(q0[3], ka.w, s0a); s0b = fmaf(q0[7], kb.w, s0b);
        float s1a = q1[0] * ka.x, s1b = q1[4] * kb.x;
        s1a = fmaf(q1[1], ka.y, s1a); s1b = fmaf(q1[5], kb.y, s1b);
        s1a = fmaf(q1[2], ka.z, s1a); s1b = fmaf(q1[6], kb.z, s1b);
        s1a = fmaf(q1[3], ka.w, s1a); s1b = fmaf(q1[7], kb.w, s1b);
        float p0 = exp2f(s0a + s0b);
        float p1 = exp2f(s1a + s1b);
        l0 += p0; l1 += p1;
        float4 va = *(const float4*)&Vs[t][0];
        float4 vb = *(const float4*)&Vs[t][4];
        a0[0] = fmaf(p0, va.x, a0[0]); a1[0] = fmaf(p1, va.x, a1[0]);
        a0[1] = fmaf(p0, va.y, a0[1]); a1[1] = fmaf(p1, va.y, a1[1]);
        a0[2] = fmaf(p0, va.z, a0[2]); a1[2] = fmaf(p1, va.z, a1[2]);
        a0[3] = fmaf(p0, va.w, a0[3]); a1[3] = fmaf(p1, va.w, a1[3]);
        a0[4] = fmaf(p0, vb.x, a0[4]); a1[4] = fmaf(p1, vb.x, a1[4]);
        a0[5] = fmaf(p0, vb.y, a0[5]); a1[5] = fmaf(p1, vb.y, a1[5]);
        a0[6] = fmaf(p0, vb.z, a0[6]); a1[6] = fmaf(p1, vb.z, a1[6]);
        a0[7] = fmaf(p0, vb.w, a0[7]); a1[7] = fmaf(p1, vb.w, a1[7]);
    }
    float inv0 = 1.0f / (l0 + 1e-30f);
    float inv1 = 1.0f / (l1 + 1e-30f);
    float* yp = y + ((size_t)n * C + h * HDIM) * HW;
#pragma unroll
    for (int d = 0; d < 8; ++d) yp[(size_t)d * HW + r0] = a0[d] * inv0;
#pragma unroll
    for (int d = 0; d < 8; ++d) yp[(size_t)d * HW + r1] = a1[d] * inv1;
}

// ---------------------------------------------------------------------------
extern "C" void kernel_launch(void* const* d_in, const int* in_sizes, int n_in,
                              void* d_out, int out_size, void* d_ws, size_t ws_size,
                              hipStream_t stream)
{
    const float* x     = (const float*)d_in[0];
    const float* gn_w  = (const float*)d_in[1];
    const float* gn_b  = (const float*)d_in[2];
    const float* qkv_w = (const float*)d_in[3];
    const float* qkv_b = (const float*)d_in[4];
    const float* out_w = (const float*)d_in[5];
    const float* out_b = (const float*)d_in[6];
    float* out = (float*)d_out;

    float* xn  = (float*)d_ws;                       // 8*256*1024
    float* qkv = xn + (size_t)NBATCH * C * HW;       // 8*768*1024
    float* y   = xn + (size_t)4 * NBATCH * C * HW;   // 8*256*1024

    gn_kernel<<<64, 256, 0, stream>>>(x, gn_w, gn_b, xn);
    gemm_bias_kernel<<<dim3(16, 12, 8), 256, 0, stream>>>(qkv_w, xn, qkv_b, qkv,
                                                          nullptr, 3 * C);
    attn_kernel<<<512, 256, 0, stream>>>(qkv, y);
    gemm_bias_kernel<<<dim3(16, 4, 8), 256, 0, stream>>>(out_w, y, out_b, out,
                                                         x, C);
}

// Round 4
// 264.810 us; speedup vs baseline: 3.1656x; 1.1672x over previous
//
#include <hip/hip_runtime.h>
#include <hip/hip_bf16.h>
#include <math.h>

// ---------------------------------------------------------------------------
// SelfAttention2d: x(8,256,32,32) -> GN(8 groups) -> qkv(768x256 GEMM)
//   -> 32 heads, d=8, attention over t=1024 -> out(256x256 GEMM) + bias + x
// Round 4: bf16 MFMA GEMMs (16x16x32, 128x128 tile, XOR-swizzled LDS),
// weights pre-cast to bf16; attention unchanged except native exp2 builtin.
// ---------------------------------------------------------------------------

#define NBATCH 8
#define C 256
#define HW 1024
#define NHEAD 32
#define HDIM 8

typedef __bf16 bf16x8 __attribute__((ext_vector_type(8)));
typedef __bf16 bf16x4 __attribute__((ext_vector_type(4)));
typedef float floatx4 __attribute__((ext_vector_type(4)));

#if __has_builtin(__builtin_amdgcn_exp2f)
#define EXP2F(x) __builtin_amdgcn_exp2f(x)
#else
#define EXP2F(x) exp2f(x)
#endif

// -------- weight convert: qkv_w (768x256) + out_w (256x256) fp32 -> bf16 ----
__global__ __launch_bounds__(256) void cvt_kernel(
    const float* __restrict__ qw, const float* __restrict__ ow,
    __bf16* __restrict__ wq, __bf16* __restrict__ wo)
{
    int id = blockIdx.x * 256 + threadIdx.x;     // 0..65535, 4 floats each
    float4 v;
    __bf16* dst;
    if (id < 49152) { v = *(const float4*)&qw[id * 4]; dst = wq + id * 4; }
    else { v = *(const float4*)&ow[(id - 49152) * 4]; dst = wo + (id - 49152) * 4; }
    bf16x4 o = { (__bf16)v.x, (__bf16)v.y, (__bf16)v.z, (__bf16)v.w };
    *(bf16x4*)dst = o;
}

// ---------------- GroupNorm: 64 blocks (n*8+g), 256 threads -----------------
__global__ __launch_bounds__(256) void gn_kernel(
    const float* __restrict__ x, const float* __restrict__ w,
    const float* __restrict__ b, float* __restrict__ xn)
{
    int n = blockIdx.x >> 3, g = blockIdx.x & 7;
    const float* xp = x + ((size_t)n * C + g * 32) * HW;
    float* op = xn + ((size_t)n * C + g * 32) * HW;
    int tid = threadIdx.x;
    const float4* xv = (const float4*)xp;
    float s = 0.f, ss = 0.f;
    for (int i = tid; i < 8192; i += 256) {
        float4 v = xv[i];
        s  += v.x + v.y + v.z + v.w;
        ss += v.x*v.x + v.y*v.y + v.z*v.z + v.w*v.w;
    }
#pragma unroll
    for (int o = 32; o; o >>= 1) { s += __shfl_xor(s, o); ss += __shfl_xor(ss, o); }
    __shared__ float rs[4], rss[4];
    int wave = tid >> 6, lane = tid & 63;
    if (lane == 0) { rs[wave] = s; rss[wave] = ss; }
    __syncthreads();
    s  = rs[0] + rs[1] + rs[2] + rs[3];
    ss = rss[0] + rss[1] + rss[2] + rss[3];
    const float invN = 1.0f / 32768.0f;
    float mean = s * invN;
    float var  = ss * invN - mean * mean;
    float rstd = rsqrtf(var + 1e-5f);
    float4* ov = (float4*)op;
    for (int i = tid; i < 8192; i += 256) {
        int c = g * 32 + (i >> 8);           // 256 float4 per channel
        float wc = w[c] * rstd;
        float bc = b[c] - mean * wc;
        float4 v = xv[i];
        float4 o4;
        o4.x = v.x * wc + bc; o4.y = v.y * wc + bc;
        o4.z = v.z * wc + bc; o4.w = v.w * wc + bc;
        ov[i] = o4;
    }
}

// ------------------- bf16 MFMA GEMM: D[n] = W * X[n] + bias -----------------
// W: bf16 [M][256] row-major. X: fp32 [256][1024] (c-major). D: fp32 [M][1024].
// 128x128 tile, BK=32, 4 waves (64x64 each, 4x4 frags of 16x16x32).
// LDS layout: per row (o or t), 32 bf16 = 4 chunks of 8; chunk q stored at
// slot q^(row&3) -> 16B-aligned ds_read_b128, bounded bank conflicts.
// B is transposed during staging (X is k-slow): 8 t-values per lane written
// as 8 scalar bf16 stores into 8 consecutive swizzled rows.
__global__ __launch_bounds__(256) void gemm_kernel(
    const __bf16* __restrict__ Wbf, const float* __restrict__ Xall,
    const float* __restrict__ bias, float* __restrict__ Call,
    const float* __restrict__ Rall, int M)
{
    int n = blockIdx.z;
    const float* X = Xall + (size_t)n * C * HW;
    float* Cp = Call + (size_t)n * M * HW;
    const float* R = Rall ? Rall + (size_t)n * C * HW : nullptr;
    int om0 = blockIdx.y * 128;
    int t0  = blockIdx.x * 128;
    __shared__ __bf16 As[128 * 32];
    __shared__ __bf16 Bs[128 * 32];
    int tid = threadIdx.x;
    int lane = tid & 63, wave = tid >> 6;
    int lrow = lane & 15, quad = lane >> 4;
    int wm = (wave & 1) * 64, wn = (wave >> 1) * 64;
    floatx4 acc[4][4] = {};
    for (int c0 = 0; c0 < C; c0 += 32) {
        // ---- stage A: 512 chunks (o, q) of 8 bf16 ----
#pragma unroll
        for (int s = 0; s < 2; ++s) {
            int id = tid + s * 256;
            int o = id >> 2, q = id & 3;
            bf16x8 av = *(const bf16x8*)&Wbf[(size_t)(om0 + o) * C + c0 + q * 8];
            *(bf16x8*)&As[o * 32 + ((q ^ (o & 3)) << 3)] = av;
        }
        // ---- stage B (transpose): 512 chunks (c, T) of 8 t ----
#pragma unroll
        for (int s = 0; s < 2; ++s) {
            int id = tid + s * 256;
            int c = id & 31, T = id >> 5;
            const float* xp = &X[(size_t)(c0 + c) * HW + t0 + T * 8];
            float4 x0 = *(const float4*)xp;
            float4 x1 = *(const float4*)(xp + 4);
            int q = c >> 3, e = c & 7;
            int tb = T * 8;                      // tb%8==0 -> (tb+i)&3 == i&3
            Bs[(tb + 0) * 32 + ((q ^ 0) << 3) + e] = (__bf16)x0.x;
            Bs[(tb + 1) * 32 + ((q ^ 1) << 3) + e] = (__bf16)x0.y;
            Bs[(tb + 2) * 32 + ((q ^ 2) << 3) + e] = (__bf16)x0.z;
            Bs[(tb + 3) * 32 + ((q ^ 3) << 3) + e] = (__bf16)x0.w;
            Bs[(tb + 4) * 32 + ((q ^ 0) << 3) + e] = (__bf16)x1.x;
            Bs[(tb + 5) * 32 + ((q ^ 1) << 3) + e] = (__bf16)x1.y;
            Bs[(tb + 6) * 32 + ((q ^ 2) << 3) + e] = (__bf16)x1.z;
            Bs[(tb + 7) * 32 + ((q ^ 3) << 3) + e] = (__bf16)x1.w;
        }
        __syncthreads();
        bf16x8 af[4], bf[4];
#pragma unroll
        for (int mi = 0; mi < 4; ++mi) {
            int o = wm + mi * 16 + lrow;
            af[mi] = *(const bf16x8*)&As[o * 32 + ((quad ^ (o & 3)) << 3)];
        }
#pragma unroll
        for (int ni = 0; ni < 4; ++ni) {
            int t = wn + ni * 16 + lrow;
            bf[ni] = *(const bf16x8*)&Bs[t * 32 + ((quad ^ (t & 3)) << 3)];
        }
#pragma unroll
        for (int mi = 0; mi < 4; ++mi)
#pragma unroll
            for (int ni = 0; ni < 4; ++ni)
                acc[mi][ni] = __builtin_amdgcn_mfma_f32_16x16x32_bf16(
                    af[mi], bf[ni], acc[mi][ni], 0, 0, 0);
        __syncthreads();
    }
    // ---- epilogue: C/D layout col=lane&15 (t), row=quad*4+reg (o) ----
#pragma unroll
    for (int mi = 0; mi < 4; ++mi) {
#pragma unroll
        for (int r = 0; r < 4; ++r) {
            int o = om0 + wm + mi * 16 + quad * 4 + r;
            float bb = bias[o];
#pragma unroll
            for (int ni = 0; ni < 4; ++ni) {
                int t = t0 + wn + ni * 16 + lrow;
                float val = acc[mi][ni][r] + bb;
                if (R) val += R[(size_t)o * HW + t];
                Cp[(size_t)o * HW + t] = val;
            }
        }
    }
}

// -------- attention: 512 blocks = (n,h,half), 256 threads, 2 rows/lane ------
// K,V staged fp32 in LDS t-major [t][8]; per-t reads are wave-uniform
// broadcasts (2x ds_read_b128 each) -> conflict-free, 4 DS instr per t.
// Softmax is lane-private (no-max: |s|<<87 for O(1)-variance inputs; exp2
// with scale*log2e folded into q). No cross-lane reductions anywhere.
__global__ __launch_bounds__(256, 4) void attn_kernel(
    const float* __restrict__ qkv, float* __restrict__ y)
{
    int bh = blockIdx.x >> 1;
    int half = blockIdx.x & 1;
    int n = bh >> 5, h = bh & 31;
    __shared__ float Ks[HW][HDIM];   // 32 KB
    __shared__ float Vs[HW][HDIM];   // 32 KB
    const float* base = qkv + (size_t)n * 3 * C * HW;
    const float* qp = base + (size_t)(h * HDIM) * HW;
    const float* kp = base + (size_t)(C + h * HDIM) * HW;
    const float* vp = base + (size_t)(2 * C + h * HDIM) * HW;
    int tid = threadIdx.x;
    for (int t = tid; t < HW; t += 256) {
        float kv[8], vv[8];
#pragma unroll
        for (int d = 0; d < 8; ++d) kv[d] = kp[(size_t)d * HW + t];
#pragma unroll
        for (int d = 0; d < 8; ++d) vv[d] = vp[(size_t)d * HW + t];
        *(float4*)&Ks[t][0] = make_float4(kv[0], kv[1], kv[2], kv[3]);
        *(float4*)&Ks[t][4] = make_float4(kv[4], kv[5], kv[6], kv[7]);
        *(float4*)&Vs[t][0] = make_float4(vv[0], vv[1], vv[2], vv[3]);
        *(float4*)&Vs[t][4] = make_float4(vv[4], vv[5], vv[6], vv[7]);
    }
    __syncthreads();
    int wave = tid >> 6, lane = tid & 63;
    int r0 = half * 512 + wave * 128 + lane;   // row 0 of this lane
    int r1 = r0 + 64;                          // row 1
    const float sl = 0.3535533905932738f * 1.4426950408889634f;
    float q0[8], q1[8];
#pragma unroll
    for (int d = 0; d < 8; ++d) q0[d] = qp[(size_t)d * HW + r0] * sl;
#pragma unroll
    for (int d = 0; d < 8; ++d) q1[d] = qp[(size_t)d * HW + r1] * sl;
    float l0 = 0.f, l1 = 0.f;
    float a0[8] = {}, a1[8] = {};
#pragma unroll 2
    for (int t = 0; t < HW; ++t) {
        float4 ka = *(const float4*)&Ks[t][0];
        float4 kb = *(const float4*)&Ks[t][4];
        float s0a = q0[0] * ka.x, s0b = q0[4] * kb.x;
        s0a = fmaf(q0[1], ka.y, s0a); s0b = fmaf(q0[5], kb.y, s0b);
        s0a = fmaf(q0[2], ka.z, s0a); s0b = fmaf(q0[6], kb.z, s0b);
        s0a = fmaf(q0[3], ka.w, s0a); s0b = fmaf(q0[7], kb.w, s0b);
        float s1a = q1[0] * ka.x, s1b = q1[4] * kb.x;
        s1a = fmaf(q1[1], ka.y, s1a); s1b = fmaf(q1[5], kb.y, s1b);
        s1a = fmaf(q1[2], ka.z, s1a); s1b = fmaf(q1[6], kb.z, s1b);
        s1a = fmaf(q1[3], ka.w, s1a); s1b = fmaf(q1[7], kb.w, s1b);
        float p0 = EXP2F(s0a + s0b);
        float p1 = EXP2F(s1a + s1b);
        l0 += p0; l1 += p1;
        float4 va = *(const float4*)&Vs[t][0];
        float4 vb = *(const float4*)&Vs[t][4];
        a0[0] = fmaf(p0, va.x, a0[0]); a1[0] = fmaf(p1, va.x, a1[0]);
        a0[1] = fmaf(p0, va.y, a0[1]); a1[1] = fmaf(p1, va.y, a1[1]);
        a0[2] = fmaf(p0, va.z, a0[2]); a1[2] = fmaf(p1, va.z, a1[2]);
        a0[3] = fmaf(p0, va.w, a0[3]); a1[3] = fmaf(p1, va.w, a1[3]);
        a0[4] = fmaf(p0, vb.x, a0[4]); a1[4] = fmaf(p1, vb.x, a1[4]);
        a0[5] = fmaf(p0, vb.y, a0[5]); a1[5] = fmaf(p1, vb.y, a1[5]);
        a0[6] = fmaf(p0, vb.z, a0[6]); a1[6] = fmaf(p1, vb.z, a1[6]);
        a0[7] = fmaf(p0, vb.w, a0[7]); a1[7] = fmaf(p1, vb.w, a1[7]);
    }
    float inv0 = 1.0f / (l0 + 1e-30f);
    float inv1 = 1.0f / (l1 + 1e-30f);
    float* yp = y + ((size_t)n * C + h * HDIM) * HW;
#pragma unroll
    for (int d = 0; d < 8; ++d) yp[(size_t)d * HW + r0] = a0[d] * inv0;
#pragma unroll
    for (int d = 0; d < 8; ++d) yp[(size_t)d * HW + r1] = a1[d] * inv1;
}

// ---------------------------------------------------------------------------
extern "C" void kernel_launch(void* const* d_in, const int* in_sizes, int n_in,
                              void* d_out, int out_size, void* d_ws, size_t ws_size,
                              hipStream_t stream)
{
    const float* x     = (const float*)d_in[0];
    const float* gn_w  = (const float*)d_in[1];
    const float* gn_b  = (const float*)d_in[2];
    const float* qkv_w = (const float*)d_in[3];
    const float* qkv_b = (const float*)d_in[4];
    const float* out_w = (const float*)d_in[5];
    const float* out_b = (const float*)d_in[6];
    float* out = (float*)d_out;

    float* xn  = (float*)d_ws;                       // 8*256*1024 f32
    float* qkv = xn + (size_t)NBATCH * C * HW;       // 8*768*1024 f32
    float* y   = xn + (size_t)4 * NBATCH * C * HW;   // 8*256*1024 f32
    __bf16* wq = (__bf16*)(y + (size_t)NBATCH * C * HW);   // 768*256 bf16
    __bf16* wo = wq + (size_t)3 * C * C;                   // 256*256 bf16

    cvt_kernel<<<256, 256, 0, stream>>>(qkv_w, out_w, wq, wo);
    gn_kernel<<<64, 256, 0, stream>>>(x, gn_w, gn_b, xn);
    gemm_kernel<<<dim3(8, 6, 8), 256, 0, stream>>>(wq, xn, qkv_b, qkv,
                                                   nullptr, 3 * C);
    attn_kernel<<<512, 256, 0, stream>>>(qkv, y);
    gemm_kernel<<<dim3(8, 2, 8), 256, 0, stream>>>(wo, y, out_b, out,
                                                   x, C);
}

// Round 5
// 194.029 us; speedup vs baseline: 4.3204x; 1.3648x over previous
//
#include <hip/hip_runtime.h>
#include <hip/hip_bf16.h>
#include <math.h>

// ---------------------------------------------------------------------------
// SelfAttention2d: x(8,256,32,32) -> GN(8 groups) -> qkv(768x256 GEMM)
//   -> 32 heads, d=8, attention over t=1024 -> out(256x256 GEMM) + bias + x
// Round 5: MFMA flash attention. QK^T via mfma_f32_32x32x16_f16 (d=8 padded),
// exp2 on C-regs, P->LDS(bf16)->A-frag, PV via mfma_f32_16x16x32_bf16 with a
// ones-column in V so Y[:,8] = rowsum(P) = softmax denominator (no reductions).
// ---------------------------------------------------------------------------

#define NBATCH 8
#define C 256
#define HW 1024
#define NHEAD 32
#define HDIM 8

typedef __bf16 bf16x8 __attribute__((ext_vector_type(8)));
typedef __bf16 bf16x4 __attribute__((ext_vector_type(4)));
typedef _Float16 f16x8 __attribute__((ext_vector_type(8)));
typedef float floatx4 __attribute__((ext_vector_type(4)));
typedef float floatx16 __attribute__((ext_vector_type(16)));

#if __has_builtin(__builtin_amdgcn_exp2f)
#define EXP2F(x) __builtin_amdgcn_exp2f(x)
#else
#define EXP2F(x) exp2f(x)
#endif

// -------- weight convert: qkv_w (768x256) + out_w (256x256) fp32 -> bf16 ----
__global__ __launch_bounds__(256) void cvt_kernel(
    const float* __restrict__ qw, const float* __restrict__ ow,
    __bf16* __restrict__ wq, __bf16* __restrict__ wo)
{
    int id = blockIdx.x * 256 + threadIdx.x;     // 0..65535, 4 floats each
    float4 v;
    __bf16* dst;
    if (id < 49152) { v = *(const float4*)&qw[id * 4]; dst = wq + id * 4; }
    else { v = *(const float4*)&ow[(id - 49152) * 4]; dst = wo + (id - 49152) * 4; }
    bf16x4 o = { (__bf16)v.x, (__bf16)v.y, (__bf16)v.z, (__bf16)v.w };
    *(bf16x4*)dst = o;
}

// ---------------- GroupNorm: 64 blocks (n*8+g), 256 threads -----------------
__global__ __launch_bounds__(256) void gn_kernel(
    const float* __restrict__ x, const float* __restrict__ w,
    const float* __restrict__ b, float* __restrict__ xn)
{
    int n = blockIdx.x >> 3, g = blockIdx.x & 7;
    const float* xp = x + ((size_t)n * C + g * 32) * HW;
    float* op = xn + ((size_t)n * C + g * 32) * HW;
    int tid = threadIdx.x;
    const float4* xv = (const float4*)xp;
    float s = 0.f, ss = 0.f;
    for (int i = tid; i < 8192; i += 256) {
        float4 v = xv[i];
        s  += v.x + v.y + v.z + v.w;
        ss += v.x*v.x + v.y*v.y + v.z*v.z + v.w*v.w;
    }
#pragma unroll
    for (int o = 32; o; o >>= 1) { s += __shfl_xor(s, o); ss += __shfl_xor(ss, o); }
    __shared__ float rs[4], rss[4];
    int wave = tid >> 6, lane = tid & 63;
    if (lane == 0) { rs[wave] = s; rss[wave] = ss; }
    __syncthreads();
    s  = rs[0] + rs[1] + rs[2] + rs[3];
    ss = rss[0] + rss[1] + rss[2] + rss[3];
    const float invN = 1.0f / 32768.0f;
    float mean = s * invN;
    float var  = ss * invN - mean * mean;
    float rstd = rsqrtf(var + 1e-5f);
    float4* ov = (float4*)op;
    for (int i = tid; i < 8192; i += 256) {
        int c = g * 32 + (i >> 8);           // 256 float4 per channel
        float wc = w[c] * rstd;
        float bc = b[c] - mean * wc;
        float4 v = xv[i];
        float4 o4;
        o4.x = v.x * wc + bc; o4.y = v.y * wc + bc;
        o4.z = v.z * wc + bc; o4.w = v.w * wc + bc;
        ov[i] = o4;
    }
}

// ------------------- bf16 MFMA GEMM: D[n] = W * X[n] + bias -----------------
// (unchanged from R4)
__global__ __launch_bounds__(256) void gemm_kernel(
    const __bf16* __restrict__ Wbf, const float* __restrict__ Xall,
    const float* __restrict__ bias, float* __restrict__ Call,
    const float* __restrict__ Rall, int M)
{
    int n = blockIdx.z;
    const float* X = Xall + (size_t)n * C * HW;
    float* Cp = Call + (size_t)n * M * HW;
    const float* R = Rall ? Rall + (size_t)n * C * HW : nullptr;
    int om0 = blockIdx.y * 128;
    int t0  = blockIdx.x * 128;
    __shared__ __bf16 As[128 * 32];
    __shared__ __bf16 Bs[128 * 32];
    int tid = threadIdx.x;
    int lane = tid & 63, wave = tid >> 6;
    int lrow = lane & 15, quad = lane >> 4;
    int wm = (wave & 1) * 64, wn = (wave >> 1) * 64;
    floatx4 acc[4][4] = {};
    for (int c0 = 0; c0 < C; c0 += 32) {
#pragma unroll
        for (int s = 0; s < 2; ++s) {
            int id = tid + s * 256;
            int o = id >> 2, q = id & 3;
            bf16x8 av = *(const bf16x8*)&Wbf[(size_t)(om0 + o) * C + c0 + q * 8];
            *(bf16x8*)&As[o * 32 + ((q ^ (o & 3)) << 3)] = av;
        }
#pragma unroll
        for (int s = 0; s < 2; ++s) {
            int id = tid + s * 256;
            int c = id & 31, T = id >> 5;
            const float* xp = &X[(size_t)(c0 + c) * HW + t0 + T * 8];
            float4 x0 = *(const float4*)xp;
            float4 x1 = *(const float4*)(xp + 4);
            int q = c >> 3, e = c & 7;
            int tb = T * 8;
            Bs[(tb + 0) * 32 + ((q ^ 0) << 3) + e] = (__bf16)x0.x;
            Bs[(tb + 1) * 32 + ((q ^ 1) << 3) + e] = (__bf16)x0.y;
            Bs[(tb + 2) * 32 + ((q ^ 2) << 3) + e] = (__bf16)x0.z;
            Bs[(tb + 3) * 32 + ((q ^ 3) << 3) + e] = (__bf16)x0.w;
            Bs[(tb + 4) * 32 + ((q ^ 0) << 3) + e] = (__bf16)x1.x;
            Bs[(tb + 5) * 32 + ((q ^ 1) << 3) + e] = (__bf16)x1.y;
            Bs[(tb + 6) * 32 + ((q ^ 2) << 3) + e] = (__bf16)x1.z;
            Bs[(tb + 7) * 32 + ((q ^ 3) << 3) + e] = (__bf16)x1.w;
        }
        __syncthreads();
        bf16x8 af[4], bf[4];
#pragma unroll
        for (int mi = 0; mi < 4; ++mi) {
            int o = wm + mi * 16 + lrow;
            af[mi] = *(const bf16x8*)&As[o * 32 + ((quad ^ (o & 3)) << 3)];
        }
#pragma unroll
        for (int ni = 0; ni < 4; ++ni) {
            int t = wn + ni * 16 + lrow;
            bf[ni] = *(const bf16x8*)&Bs[t * 32 + ((quad ^ (t & 3)) << 3)];
        }
#pragma unroll
        for (int mi = 0; mi < 4; ++mi)
#pragma unroll
            for (int ni = 0; ni < 4; ++ni)
                acc[mi][ni] = __builtin_amdgcn_mfma_f32_16x16x32_bf16(
                    af[mi], bf[ni], acc[mi][ni], 0, 0, 0);
        __syncthreads();
    }
#pragma unroll
    for (int mi = 0; mi < 4; ++mi) {
#pragma unroll
        for (int r = 0; r < 4; ++r) {
            int o = om0 + wm + mi * 16 + quad * 4 + r;
            float bb = bias[o];
#pragma unroll
            for (int ni = 0; ni < 4; ++ni) {
                int t = t0 + wn + ni * 16 + lrow;
                float val = acc[mi][ni][r] + bb;
                if (R) val += R[(size_t)o * HW + t];
                Cp[(size_t)o * HW + t] = val;
            }
        }
    }
}

// ---------------- MFMA attention: 512 blocks = (n,h,half), 4 waves ----------
// Per wave: 128 tq rows = 4 tiles of 32. Per tq-tile, sweep 32 tk-tiles:
//   S(32x32) = mfma_32x32x16_f16(Qfrag, Kfrag)   (k: d=0..7 real, 8..15 zero)
//   P = exp2(S)  (no-max softmax; scale*log2e folded into Q at staging)
//   P -> LDS bf16 tile (per-wave, stride 40 halves: aligned + 2-way banks)
//   Y(16x16 x2) += mfma_16x16x32_bf16(Pfrag, Vfrag)   (V cols: 0-7=V, 8=ones)
// Y[:,8] = rowsum(P) = l; epilogue divides via one shuffle. No K-loop barriers.
__global__ __launch_bounds__(256, 2) void attn_kernel(
    const float* __restrict__ qkv, float* __restrict__ y)
{
    int bh = blockIdx.x >> 1, half = blockIdx.x & 1;
    int n = bh >> 5, h = bh & 31;
    __shared__ alignas(16) _Float16 Kb[1024][8];    // 16 KB
    __shared__ alignas(16) _Float16 Qb[512][8];     //  8 KB
    __shared__ alignas(16) __bf16   Vb[9][1032];    // ~18 KB (stride 1032: 16B-aligned rows, 2-way banks)
    __shared__ alignas(16) __bf16   Pt[4][32][40];  // 10 KB  (stride 40: 16B-aligned, 2-way banks)
    __shared__ alignas(16) float    Zpad[4];        // 16 B of zeros (broadcast pad)
    const float* base = qkv + (size_t)n * 3 * C * HW;
    const float* qp = base + (size_t)(h * HDIM) * HW;
    const float* kp = base + (size_t)(C + h * HDIM) * HW;
    const float* vp = base + (size_t)(2 * C + h * HDIM) * HW;
    int tid = threadIdx.x;
    if (tid < 4) Zpad[tid] = 0.f;
    const float sl = 0.3535533905932738f * 1.4426950408889634f;
    // stage K (f16): lane t, 8 strided loads (coalesced per d)
    for (int t = tid; t < HW; t += 256) {
        f16x8 kv;
#pragma unroll
        for (int d = 0; d < 8; ++d) kv[d] = (_Float16)kp[(size_t)d * HW + t];
        *(f16x8*)&Kb[t][0] = kv;
    }
    // stage Q (f16, scale*log2e folded)
    for (int t = tid; t < 512; t += 256) {
        int r = half * 512 + t;
        f16x8 qv;
#pragma unroll
        for (int d = 0; d < 8; ++d) qv[d] = (_Float16)(qp[(size_t)d * HW + r] * sl);
        *(f16x8*)&Qb[t][0] = qv;
    }
    // stage V (bf16, d-major) + ones row
    for (int id = tid; id < 1024; id += 256) {
        int d = id >> 7, t0 = (id & 127) * 8;
        const float* vpp = &vp[(size_t)d * HW + t0];
        float4 a = *(const float4*)vpp;
        float4 b = *(const float4*)(vpp + 4);
        bf16x8 vv = { (__bf16)a.x, (__bf16)a.y, (__bf16)a.z, (__bf16)a.w,
                      (__bf16)b.x, (__bf16)b.y, (__bf16)b.z, (__bf16)b.w };
        *(bf16x8*)&Vb[d][t0] = vv;
    }
    if (tid < 128) {
        __bf16 one = (__bf16)1.0f;
        bf16x8 ones = { one, one, one, one, one, one, one, one };
        *(bf16x8*)&Vb[8][tid * 8] = ones;
    }
    __syncthreads();

    int lane = tid & 63, wave = tid >> 6;
    int l31 = lane & 31, lhi = lane >> 5;   // 32x32 frag coords
    int l15 = lane & 15, quad = lane >> 4;  // 16x16 frag coords
    const floatx16 zero16 = {0,0,0,0,0,0,0,0,0,0,0,0,0,0,0,0};

    for (int tqt = 0; tqt < 4; ++tqt) {
        int tq0 = wave * 128 + tqt * 32;    // row offset within this half
        // Q A-frag: A[m=l31][k=lhi*8+j]; k>=8 lanes read zeros
        const _Float16* qsrc = lhi == 0 ? &Qb[tq0 + l31][0] : (const _Float16*)Zpad;
        f16x8 qf = *(const f16x8*)qsrc;
        floatx4 accY[2] = {};
        for (int tkt = 0; tkt < 32; ++tkt) {
            int tk0 = tkt * 32;
            // K B-frag: B[k=lhi*8+j][nn=l31] = K[tk0+nn][k]
            const _Float16* ksrc = lhi == 0 ? &Kb[tk0 + l31][0] : (const _Float16*)Zpad;
            f16x8 kf = *(const f16x8*)ksrc;
            floatx16 s = __builtin_amdgcn_mfma_f32_32x32x16_f16(qf, kf, zero16, 0, 0, 0);
            // exp2 + scatter to P tile: C/D 32x32: col=l31, row=(r&3)+8*(r>>2)+4*lhi
#pragma unroll
            for (int r = 0; r < 16; ++r) {
                int prow = (r & 3) + 8 * (r >> 2) + 4 * lhi;
                Pt[wave][prow][l31] = (__bf16)EXP2F(s[r]);
            }
            asm volatile("s_waitcnt lgkmcnt(0)" ::: "memory");
            // V B-frag: B[k=quad*8+j][nn=l15] = V'[tk0+k][nn]; nn>8 -> zeros
            const __bf16* vsrc = l15 <= 8 ? &Vb[l15][tk0 + quad * 8]
                                          : (const __bf16*)Zpad;
            bf16x8 vf = *(const bf16x8*)vsrc;
#pragma unroll
            for (int mh = 0; mh < 2; ++mh) {
                // P A-frag: A[m=l15][k=quad*8+j]
                bf16x8 pf = *(const bf16x8*)&Pt[wave][mh * 16 + l15][quad * 8];
                accY[mh] = __builtin_amdgcn_mfma_f32_16x16x32_bf16(pf, vf, accY[mh], 0, 0, 0);
            }
        }
        // epilogue: C/D 16x16: col=l15 (0-7=Y dims, 8=l), row=quad*4+r
        float* yp = y + ((size_t)n * C + h * HDIM + l15) * HW;
#pragma unroll
        for (int mh = 0; mh < 2; ++mh) {
#pragma unroll
            for (int r = 0; r < 4; ++r) {
                float v = accY[mh][r];
                float lsum = __shfl(v, (lane & 48) | 8);
                if (l15 < 8) {
                    int row = half * 512 + tq0 + mh * 16 + quad * 4 + r;
                    yp[row] = v / lsum;
                }
            }
        }
    }
}

// ---------------------------------------------------------------------------
extern "C" void kernel_launch(void* const* d_in, const int* in_sizes, int n_in,
                              void* d_out, int out_size, void* d_ws, size_t ws_size,
                              hipStream_t stream)
{
    const float* x     = (const float*)d_in[0];
    const float* gn_w  = (const float*)d_in[1];
    const float* gn_b  = (const float*)d_in[2];
    const float* qkv_w = (const float*)d_in[3];
    const float* qkv_b = (const float*)d_in[4];
    const float* out_w = (const float*)d_in[5];
    const float* out_b = (const float*)d_in[6];
    float* out = (float*)d_out;

    float* xn  = (float*)d_ws;                       // 8*256*1024 f32
    float* qkv = xn + (size_t)NBATCH * C * HW;       // 8*768*1024 f32
    float* y   = xn + (size_t)4 * NBATCH * C * HW;   // 8*256*1024 f32
    __bf16* wq = (__bf16*)(y + (size_t)NBATCH * C * HW);   // 768*256 bf16
    __bf16* wo = wq + (size_t)3 * C * C;                   // 256*256 bf16

    cvt_kernel<<<256, 256, 0, stream>>>(qkv_w, out_w, wq, wo);
    gn_kernel<<<64, 256, 0, stream>>>(x, gn_w, gn_b, xn);
    gemm_kernel<<<dim3(8, 6, 8), 256, 0, stream>>>(wq, xn, qkv_b, qkv,
                                                   nullptr, 3 * C);
    attn_kernel<<<512, 256, 0, stream>>>(qkv, y);
    gemm_kernel<<<dim3(8, 2, 8), 256, 0, stream>>>(wo, y, out_b, out,
                                                   x, C);
}

// Round 6
// 167.667 us; speedup vs baseline: 4.9997x; 1.1572x over previous
//
#include <hip/hip_runtime.h>
#include <hip/hip_bf16.h>
#include <math.h>

// ---------------------------------------------------------------------------
// SelfAttention2d: x(8,256,32,32) -> GN(8 groups) -> qkv(768x256 GEMM)
//   -> 32 heads, d=8, attention over t=1024 -> out(256x256 GEMM) + bias + x
// Round 6: register-transpose MFMA attention (S^T trick, shfl_xor(32) P
// exchange, ones-column rowsum, no P LDS round-trip). Activations stored
// t-major bf16 (xnT, yT) so both GEMMs stage with pure vector copies.
// ---------------------------------------------------------------------------

#define NBATCH 8
#define C 256
#define HW 1024
#define NHEAD 32
#define HDIM 8

typedef __bf16 bf16x8 __attribute__((ext_vector_type(8)));
typedef __bf16 bf16x4 __attribute__((ext_vector_type(4)));
typedef _Float16 f16x8 __attribute__((ext_vector_type(8)));
typedef float floatx4 __attribute__((ext_vector_type(4)));
typedef float floatx16 __attribute__((ext_vector_type(16)));

#if __has_builtin(__builtin_amdgcn_exp2f)
#define EXP2F(x) __builtin_amdgcn_exp2f(x)
#else
#define EXP2F(x) exp2f(x)
#endif

// -------- weight convert: qkv_w (768x256) + out_w (256x256) fp32 -> bf16 ----
__global__ __launch_bounds__(256) void cvt_kernel(
    const float* __restrict__ qw, const float* __restrict__ ow,
    __bf16* __restrict__ wq, __bf16* __restrict__ wo)
{
    int id = blockIdx.x * 256 + threadIdx.x;     // 0..65535, 4 floats each
    float4 v;
    __bf16* dst;
    if (id < 49152) { v = *(const float4*)&qw[id * 4]; dst = wq + id * 4; }
    else { v = *(const float4*)&ow[(id - 49152) * 4]; dst = wo + (id - 49152) * 4; }
    bf16x4 o = { (__bf16)v.x, (__bf16)v.y, (__bf16)v.z, (__bf16)v.w };
    *(bf16x4*)dst = o;
}

// ---- GroupNorm -> xnT bf16 [n][t][c] (transpose via LDS), 64 blocks --------
__global__ __launch_bounds__(256) void gn_kernel(
    const float* __restrict__ x, const float* __restrict__ w,
    const float* __restrict__ b, __bf16* __restrict__ xnT)
{
    int n = blockIdx.x >> 3, g = blockIdx.x & 7;
    const float* xp = x + ((size_t)n * C + g * 32) * HW;
    int tid = threadIdx.x;
    const float4* xv = (const float4*)xp;
    float s = 0.f, ss = 0.f;
    for (int i = tid; i < 8192; i += 256) {
        float4 v = xv[i];
        s  += v.x + v.y + v.z + v.w;
        ss += v.x*v.x + v.y*v.y + v.z*v.z + v.w*v.w;
    }
#pragma unroll
    for (int o = 32; o; o >>= 1) { s += __shfl_xor(s, o); ss += __shfl_xor(ss, o); }
    __shared__ float rs[4], rss[4];
    int wave = tid >> 6, lane = tid & 63;
    if (lane == 0) { rs[wave] = s; rss[wave] = ss; }
    __syncthreads();
    s  = rs[0] + rs[1] + rs[2] + rs[3];
    ss = rss[0] + rss[1] + rss[2] + rss[3];
    const float invN = 1.0f / 32768.0f;
    float mean = s * invN;
    float var  = ss * invN - mean * mean;
    float rstd = rsqrtf(var + 1e-5f);
    // normalize + transpose: 4 chunks of 256 t
    __shared__ __bf16 Lt[32][257];              // +1 pad: spreads banks
    __bf16* xo = xnT + (size_t)n * HW * C + g * 32;
    for (int ch = 0; ch < 4; ++ch) {
        int t0 = ch * 256;
        __syncthreads();                        // protect Lt reuse
#pragma unroll 8
        for (int c = 0; c < 32; ++c) {
            float wc = w[g * 32 + c] * rstd;
            float bc = b[g * 32 + c] - mean * wc;
            float v = xp[(size_t)c * HW + t0 + tid];
            Lt[c][tid] = (__bf16)(v * wc + bc);
        }
        __syncthreads();
#pragma unroll
        for (int q = 0; q < 4; ++q) {
            bf16x8 o;
#pragma unroll
            for (int e = 0; e < 8; ++e) o[e] = Lt[q * 8 + e][tid];
            *(bf16x8*)&xo[(size_t)(t0 + tid) * C + q * 8] = o;
        }
    }
}

// ---- bf16 MFMA GEMM: D[n][o][t] = W(Mx256) * actT[n](1024x256)^T + bias ----
// A = W row-major [o][c]; B = actT t-major [t][c] (B[k=c][n=t] frag = lane t
// holds 8 consecutive c -> both operands stage as pure bf16x8 copies).
// 128x128 tile, BK=32, XOR-chunk swizzle, 4 waves of 64x64 (4x4 frags).
__global__ __launch_bounds__(256) void gemm_kernel(
    const __bf16* __restrict__ W, const __bf16* __restrict__ Ball,
    const float* __restrict__ bias, float* __restrict__ Call,
    const float* __restrict__ Rall, int M)
{
    int n = blockIdx.z;
    const __bf16* B = Ball + (size_t)n * HW * C;
    float* Cp = Call + (size_t)n * M * HW;
    const float* R = Rall ? Rall + (size_t)n * C * HW : nullptr;
    int om0 = blockIdx.y * 128, t0 = blockIdx.x * 128;
    __shared__ __bf16 As[128 * 32];
    __shared__ __bf16 Bs[128 * 32];
    int tid = threadIdx.x, lane = tid & 63, wave = tid >> 6;
    int l15 = lane & 15, quad = lane >> 4;
    int wm = (wave & 1) * 64, wn = (wave >> 1) * 64;
    int swq = (quad ^ (l15 & 3)) * 8;           // frag-read swizzle (row&3 == l15&3)
    floatx4 acc[4][4] = {};
    for (int c0 = 0; c0 < C; c0 += 32) {
        bf16x8 av[2], bv[2];
#pragma unroll
        for (int sIt = 0; sIt < 2; ++sIt) {
            int id = tid + sIt * 256;
            int row = id >> 2, q = id & 3;
            av[sIt] = *(const bf16x8*)&W[(size_t)(om0 + row) * C + c0 + q * 8];
            bv[sIt] = *(const bf16x8*)&B[(size_t)(t0 + row) * C + c0 + q * 8];
        }
        __syncthreads();                        // prev-iter frag reads done
#pragma unroll
        for (int sIt = 0; sIt < 2; ++sIt) {
            int id = tid + sIt * 256;
            int row = id >> 2, q = id & 3;
            int sw = ((q ^ (row & 3)) * 8);
            *(bf16x8*)&As[row * 32 + sw] = av[sIt];
            *(bf16x8*)&Bs[row * 32 + sw] = bv[sIt];
        }
        __syncthreads();
        bf16x8 af[4], bfr[4];
#pragma unroll
        for (int mi = 0; mi < 4; ++mi)
            af[mi] = *(const bf16x8*)&As[(wm + mi * 16 + l15) * 32 + swq];
#pragma unroll
        for (int ni = 0; ni < 4; ++ni)
            bfr[ni] = *(const bf16x8*)&Bs[(wn + ni * 16 + l15) * 32 + swq];
#pragma unroll
        for (int mi = 0; mi < 4; ++mi)
#pragma unroll
            for (int ni = 0; ni < 4; ++ni)
                acc[mi][ni] = __builtin_amdgcn_mfma_f32_16x16x32_bf16(
                    af[mi], bfr[ni], acc[mi][ni], 0, 0, 0);
    }
    // epilogue: D col = lane l15 = t, row = quad*4+r = o
#pragma unroll
    for (int mi = 0; mi < 4; ++mi) {
#pragma unroll
        for (int r = 0; r < 4; ++r) {
            int o = om0 + wm + mi * 16 + quad * 4 + r;
            float bb = bias[o];
#pragma unroll
            for (int ni = 0; ni < 4; ++ni) {
                int t = t0 + wn + ni * 16 + l15;
                float val = acc[mi][ni][r] + bb;
                if (R) val += R[(size_t)o * HW + t];
                Cp[(size_t)o * HW + t] = val;
            }
        }
    }
}

// ---- MFMA attention, register-transpose: 1024 blocks = (n,h,quarter) -------
// S^T = mfma_32x32x16_f16(A=K, B=Q)  (Q lanes k>=8 zeroed; K upper-k garbage
// is cancelled). C-layout: col=tq=lane&31, row=tk=(r&3)+8(r>>2)+4*(lane>>5).
// P^T-as-B frag for PV == one lane^32 exchange of packed bf16 quads.
// PV: Y^T = mfma_32x32x16_bf16(A=Vd (d-major, row8=ones), B=P^T); Y^T row 8 =
// rowsum(P) = softmax denom. A-rows 9..31 garbage-tolerant (only rows 0..8 read).
__global__ __launch_bounds__(256, 4) void attn_kernel(
    const float* __restrict__ qkv, __bf16* __restrict__ yT)
{
    int quarter = blockIdx.x & 3, h = (blockIdx.x >> 2) & 31, n = blockIdx.x >> 7;
    __shared__ alignas(16) _Float16 Kb[HW][8];        // 16 KB
    __shared__ alignas(16) __bf16   Vb[9][HW + 8];    // ~18.1 KB, stride 1032
    const float* base = qkv + (size_t)n * 3 * C * HW;
    const float* qp = base + (size_t)(h * HDIM) * HW;
    const float* kp = base + (size_t)(C + h * HDIM) * HW;
    const float* vp = base + (size_t)(2 * C + h * HDIM) * HW;
    int tid = threadIdx.x;
    for (int t = tid; t < HW; t += 256) {
        f16x8 kv;
#pragma unroll
        for (int d = 0; d < 8; ++d) kv[d] = (_Float16)kp[(size_t)d * HW + t];
        *(f16x8*)&Kb[t][0] = kv;
    }
    for (int id = tid; id < 1024; id += 256) {
        int d = id >> 7, t8 = (id & 127) * 8;
        const float* vpp = &vp[(size_t)d * HW + t8];
        float4 a = *(const float4*)vpp;
        float4 b2 = *(const float4*)(vpp + 4);
        bf16x8 vv = { (__bf16)a.x, (__bf16)a.y, (__bf16)a.z, (__bf16)a.w,
                      (__bf16)b2.x, (__bf16)b2.y, (__bf16)b2.z, (__bf16)b2.w };
        *(bf16x8*)&Vb[d][t8] = vv;
    }
    if (tid < 128) {
        __bf16 one = (__bf16)1.0f;
        bf16x8 ones = { one, one, one, one, one, one, one, one };
        *(bf16x8*)&Vb[8][tid * 8] = ones;
    }
    __syncthreads();

    int lane = tid & 63, wave = tid >> 6;
    int l31 = lane & 31, lhi = lane >> 5;
    int vrow = l31 < 9 ? l31 : (l31 & 7);       // rows >8 garbage-tolerant
    const __bf16* vbase = &Vb[vrow][0];
    const float sl = 0.3535533905932738f * 1.4426950408889634f; // scale*log2e
    int tqb = quarter * 256 + wave * 64;
    f16x8 qf[2];
#pragma unroll
    for (int tau = 0; tau < 2; ++tau) {
        f16x8 qv = { 0, 0, 0, 0, 0, 0, 0, 0 };
        if (lhi == 0) {
#pragma unroll
            for (int d = 0; d < 8; ++d)
                qv[d] = (_Float16)(qp[(size_t)d * HW + tqb + tau * 32 + l31] * sl);
        }
        qf[tau] = qv;
    }
    floatx16 accG[2] = {};
    floatx16 zero16 = {};
    for (int tkt = 0; tkt < 32; ++tkt) {
        f16x8 kf = *(const f16x8*)&Kb[tkt * 32 + l31][0];
        bf16x8 vf0 = *(const bf16x8*)&vbase[tkt * 32 + lhi * 8];
        bf16x8 vf1 = *(const bf16x8*)&vbase[tkt * 32 + 16 + lhi * 8];
#pragma unroll
        for (int tau = 0; tau < 2; ++tau) {
            floatx16 sT = __builtin_amdgcn_mfma_f32_32x32x16_f16(
                kf, qf[tau], zero16, 0, 0, 0);
            __bf16 p[16];
#pragma unroll
            for (int r = 0; r < 16; ++r) p[r] = (__bf16)EXP2F(sT[r]);
            bf16x4 g0 = { p[0], p[1], p[2], p[3] };
            bf16x4 g1 = { p[4], p[5], p[6], p[7] };
            bf16x4 g2 = { p[8], p[9], p[10], p[11] };
            bf16x4 g3 = { p[12], p[13], p[14], p[15] };
            bf16x4 s0 = lhi ? g0 : g1;          // send own quad partner needs
            bf16x4 s1 = lhi ? g2 : g3;
            int2 s0i = __builtin_bit_cast(int2, s0);
            int2 s1i = __builtin_bit_cast(int2, s1);
            int2 r0i, r1i;
            r0i.x = __shfl_xor(s0i.x, 32); r0i.y = __shfl_xor(s0i.y, 32);
            r1i.x = __shfl_xor(s1i.x, 32); r1i.y = __shfl_xor(s1i.y, 32);
            bf16x4 r0 = __builtin_bit_cast(bf16x4, r0i);
            bf16x4 r1 = __builtin_bit_cast(bf16x4, r1i);
            bf16x4 lo0 = lhi ? r0 : g0, hi0 = lhi ? g1 : r0;
            bf16x4 lo1 = lhi ? r1 : g2, hi1 = lhi ? g3 : r1;
            bf16x8 P0 = __builtin_shufflevector(lo0, hi0, 0, 1, 2, 3, 4, 5, 6, 7);
            bf16x8 P1 = __builtin_shufflevector(lo1, hi1, 0, 1, 2, 3, 4, 5, 6, 7);
            accG[tau] = __builtin_amdgcn_mfma_f32_32x32x16_bf16(
                vf0, P0, accG[tau], 0, 0, 0);
            accG[tau] = __builtin_amdgcn_mfma_f32_32x32x16_bf16(
                vf1, P1, accG[tau], 0, 0, 0);
        }
    }
    // epilogue: Y^T col = tq = l31; rows r0-3 = d (0-3 | 4-7 by lhi); r4 (lhi=0) = lsum
    __bf16* yp = yT + (size_t)n * HW * C + h * HDIM + lhi * 4;
#pragma unroll
    for (int tau = 0; tau < 2; ++tau) {
        float own4 = accG[tau][4];
        float part4 = __shfl_xor(own4, 32);
        float lsum = lhi ? part4 : own4;
        float inv = 1.0f / lsum;
        bf16x4 o = { (__bf16)(accG[tau][0] * inv), (__bf16)(accG[tau][1] * inv),
                     (__bf16)(accG[tau][2] * inv), (__bf16)(accG[tau][3] * inv) };
        *(bf16x4*)&yp[(size_t)(tqb + tau * 32 + l31) * C] = o;
    }
}

// ---------------------------------------------------------------------------
extern "C" void kernel_launch(void* const* d_in, const int* in_sizes, int n_in,
                              void* d_out, int out_size, void* d_ws, size_t ws_size,
                              hipStream_t stream)
{
    const float* x     = (const float*)d_in[0];
    const float* gn_w  = (const float*)d_in[1];
    const float* gn_b  = (const float*)d_in[2];
    const float* qkv_w = (const float*)d_in[3];
    const float* qkv_b = (const float*)d_in[4];
    const float* out_w = (const float*)d_in[5];
    const float* out_b = (const float*)d_in[6];
    float* out = (float*)d_out;

    char* wsb = (char*)d_ws;
    __bf16* xnT = (__bf16*)wsb;                         // 8*1024*256 bf16 = 4MB
    float*  qkv = (float*)(wsb + ((size_t)4 << 20));    // 8*768*1024 f32 = 24MB
    __bf16* yTp = (__bf16*)(wsb + ((size_t)28 << 20));  // 8*1024*256 bf16 = 4MB
    __bf16* wq  = (__bf16*)(wsb + ((size_t)32 << 20));  // 768*256 bf16
    __bf16* wo  = wq + (size_t)3 * C * C;               // 256*256 bf16

    cvt_kernel<<<256, 256, 0, stream>>>(qkv_w, out_w, wq, wo);
    gn_kernel<<<64, 256, 0, stream>>>(x, gn_w, gn_b, xnT);
    gemm_kernel<<<dim3(8, 6, 8), 256, 0, stream>>>(wq, xnT, qkv_b, qkv,
                                                   nullptr, 3 * C);
    attn_kernel<<<1024, 256, 0, stream>>>(qkv, yTp);
    gemm_kernel<<<dim3(8, 2, 8), 256, 0, stream>>>(wo, yTp, out_b, out,
                                                   x, C);
}

// Round 7
// 145.533 us; speedup vs baseline: 5.7601x; 1.1521x over previous
//
#include <hip/hip_runtime.h>
#include <hip/hip_bf16.h>
#include <math.h>

// ---------------------------------------------------------------------------
// SelfAttention2d: x(8,256,32,32) -> GN(8 groups) -> qkv(768x256 GEMM)
//   -> 32 heads, d=8, attention over t=1024 -> out(256x256 GEMM) + bias + x
// Round 7: qkv GEMM emits attention-native layouts (Q f16 [h][t][8] pre-scaled,
// K f16 [h][t][8], V bf16 [h*8][t]) so attn stages with pure vector copies and
// loads Q straight to fragments. GEMM tiles 64x128 (qkv: 768 blocks = 3/CU).
// ---------------------------------------------------------------------------

#define NBATCH 8
#define C 256
#define HW 1024
#define NHEAD 32
#define HDIM 8

typedef __bf16 bf16x8 __attribute__((ext_vector_type(8)));
typedef __bf16 bf16x4 __attribute__((ext_vector_type(4)));
typedef _Float16 f16x8 __attribute__((ext_vector_type(8)));
typedef _Float16 f16x4 __attribute__((ext_vector_type(4)));
typedef float floatx4 __attribute__((ext_vector_type(4)));
typedef float floatx16 __attribute__((ext_vector_type(16)));

#if __has_builtin(__builtin_amdgcn_exp2f)
#define EXP2F(x) __builtin_amdgcn_exp2f(x)
#else
#define EXP2F(x) exp2f(x)
#endif

#define SCALE_LOG2E 0.51013249662f   // (1/sqrt(8)) * log2(e)

// -------- weight convert: qkv_w (768x256) + out_w (256x256) fp32 -> bf16 ----
__global__ __launch_bounds__(256) void cvt_kernel(
    const float* __restrict__ qw, const float* __restrict__ ow,
    __bf16* __restrict__ wq, __bf16* __restrict__ wo)
{
    int id = blockIdx.x * 256 + threadIdx.x;     // 0..65535, 4 floats each
    float4 v;
    __bf16* dst;
    if (id < 49152) { v = *(const float4*)&qw[id * 4]; dst = wq + id * 4; }
    else { v = *(const float4*)&ow[(id - 49152) * 4]; dst = wo + (id - 49152) * 4; }
    bf16x4 o = { (__bf16)v.x, (__bf16)v.y, (__bf16)v.z, (__bf16)v.w };
    *(bf16x4*)dst = o;
}

// ---- GroupNorm -> xnT bf16 [n][t][c] (transpose via LDS), 64 blocks --------
__global__ __launch_bounds__(256) void gn_kernel(
    const float* __restrict__ x, const float* __restrict__ w,
    const float* __restrict__ b, __bf16* __restrict__ xnT)
{
    int n = blockIdx.x >> 3, g = blockIdx.x & 7;
    const float* xp = x + ((size_t)n * C + g * 32) * HW;
    int tid = threadIdx.x;
    const float4* xv = (const float4*)xp;
    float s = 0.f, ss = 0.f;
    for (int i = tid; i < 8192; i += 256) {
        float4 v = xv[i];
        s  += v.x + v.y + v.z + v.w;
        ss += v.x*v.x + v.y*v.y + v.z*v.z + v.w*v.w;
    }
#pragma unroll
    for (int o = 32; o; o >>= 1) { s += __shfl_xor(s, o); ss += __shfl_xor(ss, o); }
    __shared__ float rs[4], rss[4];
    int wave = tid >> 6, lane = tid & 63;
    if (lane == 0) { rs[wave] = s; rss[wave] = ss; }
    __syncthreads();
    s  = rs[0] + rs[1] + rs[2] + rs[3];
    ss = rss[0] + rss[1] + rss[2] + rss[3];
    const float invN = 1.0f / 32768.0f;
    float mean = s * invN;
    float var  = ss * invN - mean * mean;
    float rstd = rsqrtf(var + 1e-5f);
    __shared__ __bf16 Lt[32][257];
    __bf16* xo = xnT + (size_t)n * HW * C + g * 32;
    for (int ch = 0; ch < 4; ++ch) {
        int t0 = ch * 256;
        __syncthreads();
#pragma unroll 8
        for (int c = 0; c < 32; ++c) {
            float wc = w[g * 32 + c] * rstd;
            float bc = b[g * 32 + c] - mean * wc;
            float v = xp[(size_t)c * HW + t0 + tid];
            Lt[c][tid] = (__bf16)(v * wc + bc);
        }
        __syncthreads();
#pragma unroll
        for (int q = 0; q < 4; ++q) {
            bf16x8 o;
#pragma unroll
            for (int e = 0; e < 8; ++e) o[e] = Lt[q * 8 + e][tid];
            *(bf16x8*)&xo[(size_t)(t0 + tid) * C + q * 8] = o;
        }
    }
}

// ---- qkv GEMM: 64x128 tile, 4 waves of 32x64; scatter epilogue -------------
// A = qkv_w bf16 [o][c]; B = xnT bf16 [t][c]. Outputs:
//   o<256  -> Qf f16 [n][h][t][8], value*(scale*log2e)
//   o<512  -> Kf f16 [n][h][t][8]
//   else   -> Vb bf16 [n][o-512][t]  (d-major)
__global__ __launch_bounds__(256) void gemm_qkv_kernel(
    const __bf16* __restrict__ W, const __bf16* __restrict__ Ball,
    const float* __restrict__ bias, _Float16* __restrict__ Qf,
    _Float16* __restrict__ Kf, __bf16* __restrict__ Vbf)
{
    int n = blockIdx.z;
    const __bf16* B = Ball + (size_t)n * HW * C;
    int om0 = blockIdx.y * 64, t0 = blockIdx.x * 128;
    __shared__ __bf16 As[64 * 32];
    __shared__ __bf16 Bs[128 * 32];
    int tid = threadIdx.x, lane = tid & 63, wave = tid >> 6;
    int l15 = lane & 15, quad = lane >> 4;
    int wm = (wave & 1) * 32, wn = (wave >> 1) * 64;
    int swq = (quad ^ (l15 & 3)) * 8;
    int arow = tid >> 2, aq = tid & 3;
    int sw = (aq ^ (arow & 3)) * 8;
    floatx4 acc[2][4] = {};
    for (int c0 = 0; c0 < C; c0 += 32) {
        bf16x8 av  = *(const bf16x8*)&W[(size_t)(om0 + arow) * C + c0 + aq * 8];
        bf16x8 bv0 = *(const bf16x8*)&B[(size_t)(t0 + arow) * C + c0 + aq * 8];
        bf16x8 bv1 = *(const bf16x8*)&B[(size_t)(t0 + 64 + arow) * C + c0 + aq * 8];
        __syncthreads();
        *(bf16x8*)&As[arow * 32 + sw] = av;
        *(bf16x8*)&Bs[arow * 32 + sw] = bv0;
        *(bf16x8*)&Bs[(arow + 64) * 32 + sw] = bv1;   // (arow+64)&3 == arow&3
        __syncthreads();
        bf16x8 af[2], bfr[4];
#pragma unroll
        for (int mi = 0; mi < 2; ++mi)
            af[mi] = *(const bf16x8*)&As[(wm + mi * 16 + l15) * 32 + swq];
#pragma unroll
        for (int ni = 0; ni < 4; ++ni)
            bfr[ni] = *(const bf16x8*)&Bs[(wn + ni * 16 + l15) * 32 + swq];
#pragma unroll
        for (int mi = 0; mi < 2; ++mi)
#pragma unroll
            for (int ni = 0; ni < 4; ++ni)
                acc[mi][ni] = __builtin_amdgcn_mfma_f32_16x16x32_bf16(
                    af[mi], bfr[ni], acc[mi][ni], 0, 0, 0);
    }
#pragma unroll
    for (int mi = 0; mi < 2; ++mi) {
        int obase = om0 + wm + mi * 16;         // multiple of 16: Q/K/V uniform
        int oq = obase + quad * 4;              // first of 4 consecutive o
        if (obase < 512) {                      // Q or K: f16x4 [h][t][d0..d0+3]
            int h  = (oq & 255) >> 3;
            int d0 = (quad & 1) * 4;
            _Float16* dst = (obase < 256 ? Qf : Kf);
            float mul = (obase < 256) ? SCALE_LOG2E : 1.0f;
#pragma unroll
            for (int ni = 0; ni < 4; ++ni) {
                int t = t0 + wn + ni * 16 + l15;
                f16x4 o;
#pragma unroll
                for (int r = 0; r < 4; ++r)
                    o[r] = (_Float16)((acc[mi][ni][r] + bias[oq + r]) * mul);
                *(f16x4*)&dst[(((size_t)(n * 32 + h)) * HW + t) * 8 + d0] = o;
            }
        } else {                                // V: bf16 [c][t] scalar stores
            int cv = oq - 512;
#pragma unroll
            for (int ni = 0; ni < 4; ++ni) {
                int t = t0 + wn + ni * 16 + l15;
#pragma unroll
                for (int r = 0; r < 4; ++r)
                    Vbf[((size_t)(n * 256 + cv + r)) * HW + t] =
                        (__bf16)(acc[mi][ni][r] + bias[oq + r]);
            }
        }
    }
}

// ---- out GEMM: 64x128 tile, 4 waves of 32x64; f32 + bias + residual --------
__global__ __launch_bounds__(256) void gemm_out_kernel(
    const __bf16* __restrict__ W, const __bf16* __restrict__ Ball,
    const float* __restrict__ bias, float* __restrict__ Call,
    const float* __restrict__ Rall)
{
    int n = blockIdx.z;
    const __bf16* B = Ball + (size_t)n * HW * C;
    float* Cp = Call + (size_t)n * C * HW;
    const float* R = Rall + (size_t)n * C * HW;
    int om0 = blockIdx.y * 64, t0 = blockIdx.x * 128;
    __shared__ __bf16 As[64 * 32];
    __shared__ __bf16 Bs[128 * 32];
    int tid = threadIdx.x, lane = tid & 63, wave = tid >> 6;
    int l15 = lane & 15, quad = lane >> 4;
    int wm = (wave & 1) * 32, wn = (wave >> 1) * 64;
    int swq = (quad ^ (l15 & 3)) * 8;
    int arow = tid >> 2, aq = tid & 3;
    int sw = (aq ^ (arow & 3)) * 8;
    floatx4 acc[2][4] = {};
    for (int c0 = 0; c0 < C; c0 += 32) {
        bf16x8 av  = *(const bf16x8*)&W[(size_t)(om0 + arow) * C + c0 + aq * 8];
        bf16x8 bv0 = *(const bf16x8*)&B[(size_t)(t0 + arow) * C + c0 + aq * 8];
        bf16x8 bv1 = *(const bf16x8*)&B[(size_t)(t0 + 64 + arow) * C + c0 + aq * 8];
        __syncthreads();
        *(bf16x8*)&As[arow * 32 + sw] = av;
        *(bf16x8*)&Bs[arow * 32 + sw] = bv0;
        *(bf16x8*)&Bs[(arow + 64) * 32 + sw] = bv1;
        __syncthreads();
        bf16x8 af[2], bfr[4];
#pragma unroll
        for (int mi = 0; mi < 2; ++mi)
            af[mi] = *(const bf16x8*)&As[(wm + mi * 16 + l15) * 32 + swq];
#pragma unroll
        for (int ni = 0; ni < 4; ++ni)
            bfr[ni] = *(const bf16x8*)&Bs[(wn + ni * 16 + l15) * 32 + swq];
#pragma unroll
        for (int mi = 0; mi < 2; ++mi)
#pragma unroll
            for (int ni = 0; ni < 4; ++ni)
                acc[mi][ni] = __builtin_amdgcn_mfma_f32_16x16x32_bf16(
                    af[mi], bfr[ni], acc[mi][ni], 0, 0, 0);
    }
#pragma unroll
    for (int mi = 0; mi < 2; ++mi) {
#pragma unroll
        for (int r = 0; r < 4; ++r) {
            int o = om0 + wm + mi * 16 + quad * 4 + r;
            float bb = bias[o];
#pragma unroll
            for (int ni = 0; ni < 4; ++ni) {
                int t = t0 + wn + ni * 16 + l15;
                Cp[(size_t)o * HW + t] = acc[mi][ni][r] + bb + R[(size_t)o * HW + t];
            }
        }
    }
}

// ---- MFMA attention, register-transpose: 1024 blocks = (n,h,quarter) -------
// Q/K f16 [h][t][8] pre-formatted, V bf16 [h*8][t] d-major. All staging is
// pure 16B vector copies; Q goes straight to fragments. S^T = mfma(A=K,B=Q),
// exp2 on C-regs, lane^32 exchange -> P^T B-frag, PV via mfma(A=Vd rows + ones
// row 8 => Y^T row 8 = softmax denom).
__global__ __launch_bounds__(256, 4) void attn_kernel(
    const _Float16* __restrict__ Qf, const _Float16* __restrict__ Kf,
    const __bf16* __restrict__ Vg, __bf16* __restrict__ yT)
{
    int quarter = blockIdx.x & 3, h = (blockIdx.x >> 2) & 31, n = blockIdx.x >> 7;
    __shared__ alignas(16) _Float16 Kb[HW][8];        // 16 KB
    __shared__ alignas(16) __bf16   Vb[9][HW + 8];    // ~18.1 KB, stride 1032
    int tid = threadIdx.x;
    const _Float16* kg = Kf + ((size_t)(n * 32 + h)) * HW * 8;
    const __bf16*   vg = Vg + ((size_t)(n * 256 + h * 8)) * HW;
#pragma unroll
    for (int i = 0; i < 4; ++i) {
        int row = tid + i * 256;
        *(f16x8*)&Kb[row][0] = *(const f16x8*)&kg[(size_t)row * 8];
    }
#pragma unroll
    for (int i = 0; i < 4; ++i) {
        int id = tid + i * 256;
        int d = id >> 7, t8 = (id & 127) * 8;
        *(bf16x8*)&Vb[d][t8] = *(const bf16x8*)&vg[(size_t)d * HW + t8];
    }
    if (tid < 128) {
        __bf16 one = (__bf16)1.0f;
        bf16x8 ones = { one, one, one, one, one, one, one, one };
        *(bf16x8*)&Vb[8][tid * 8] = ones;
    }
    int lane = tid & 63, wave = tid >> 6;
    int l31 = lane & 31, lhi = lane >> 5;
    int vrow = l31 < 9 ? l31 : (l31 & 7);
    const __bf16* vbase = &Vb[vrow][0];
    int tqb = quarter * 256 + wave * 64;
    const _Float16* qg = Qf + ((size_t)(n * 32 + h)) * HW * 8;
    f16x8 qf[2];
#pragma unroll
    for (int tau = 0; tau < 2; ++tau) {
        f16x8 qv = { 0, 0, 0, 0, 0, 0, 0, 0 };
        if (lhi == 0)
            qv = *(const f16x8*)&qg[(size_t)(tqb + tau * 32 + l31) * 8];
        qf[tau] = qv;
    }
    __syncthreads();
    floatx16 accG[2] = {};
    floatx16 zero16 = {};
    for (int tkt = 0; tkt < 32; ++tkt) {
        f16x8 kf = *(const f16x8*)&Kb[tkt * 32 + l31][0];
        bf16x8 vf0 = *(const bf16x8*)&vbase[tkt * 32 + lhi * 8];
        bf16x8 vf1 = *(const bf16x8*)&vbase[tkt * 32 + 16 + lhi * 8];
#pragma unroll
        for (int tau = 0; tau < 2; ++tau) {
            floatx16 sT = __builtin_amdgcn_mfma_f32_32x32x16_f16(
                kf, qf[tau], zero16, 0, 0, 0);
            __bf16 p[16];
#pragma unroll
            for (int r = 0; r < 16; ++r) p[r] = (__bf16)EXP2F(sT[r]);
            bf16x4 g0 = { p[0], p[1], p[2], p[3] };
            bf16x4 g1 = { p[4], p[5], p[6], p[7] };
            bf16x4 g2 = { p[8], p[9], p[10], p[11] };
            bf16x4 g3 = { p[12], p[13], p[14], p[15] };
            bf16x4 s0 = lhi ? g0 : g1;
            bf16x4 s1 = lhi ? g2 : g3;
            int2 s0i = __builtin_bit_cast(int2, s0);
            int2 s1i = __builtin_bit_cast(int2, s1);
            int2 r0i, r1i;
            r0i.x = __shfl_xor(s0i.x, 32); r0i.y = __shfl_xor(s0i.y, 32);
            r1i.x = __shfl_xor(s1i.x, 32); r1i.y = __shfl_xor(s1i.y, 32);
            bf16x4 r0 = __builtin_bit_cast(bf16x4, r0i);
            bf16x4 r1 = __builtin_bit_cast(bf16x4, r1i);
            bf16x4 lo0 = lhi ? r0 : g0, hi0 = lhi ? g1 : r0;
            bf16x4 lo1 = lhi ? r1 : g2, hi1 = lhi ? g3 : r1;
            bf16x8 P0 = __builtin_shufflevector(lo0, hi0, 0, 1, 2, 3, 4, 5, 6, 7);
            bf16x8 P1 = __builtin_shufflevector(lo1, hi1, 0, 1, 2, 3, 4, 5, 6, 7);
            accG[tau] = __builtin_amdgcn_mfma_f32_32x32x16_bf16(
                vf0, P0, accG[tau], 0, 0, 0);
            accG[tau] = __builtin_amdgcn_mfma_f32_32x32x16_bf16(
                vf1, P1, accG[tau], 0, 0, 0);
        }
    }
    __bf16* yp = yT + (size_t)n * HW * C + h * HDIM + lhi * 4;
#pragma unroll
    for (int tau = 0; tau < 2; ++tau) {
        float own4 = accG[tau][4];
        float part4 = __shfl_xor(own4, 32);
        float lsum = lhi ? part4 : own4;
        float inv = 1.0f / lsum;
        bf16x4 o = { (__bf16)(accG[tau][0] * inv), (__bf16)(accG[tau][1] * inv),
                     (__bf16)(accG[tau][2] * inv), (__bf16)(accG[tau][3] * inv) };
        *(bf16x4*)&yp[(size_t)(tqb + tau * 32 + l31) * C] = o;
    }
}

// ---------------------------------------------------------------------------
extern "C" void kernel_launch(void* const* d_in, const int* in_sizes, int n_in,
                              void* d_out, int out_size, void* d_ws, size_t ws_size,
                              hipStream_t stream)
{
    const float* x     = (const float*)d_in[0];
    const float* gn_w  = (const float*)d_in[1];
    const float* gn_b  = (const float*)d_in[2];
    const float* qkv_w = (const float*)d_in[3];
    const float* qkv_b = (const float*)d_in[4];
    const float* out_w = (const float*)d_in[5];
    const float* out_b = (const float*)d_in[6];
    float* out = (float*)d_out;

    char* wsb = (char*)d_ws;
    __bf16*   xnT = (__bf16*)wsb;                        // 4 MB
    _Float16* Qf  = (_Float16*)(wsb + ((size_t)4 << 20)); // 4 MB
    _Float16* Kf  = (_Float16*)(wsb + ((size_t)8 << 20)); // 4 MB
    __bf16*   Vbf = (__bf16*)(wsb + ((size_t)12 << 20));  // 4 MB
    __bf16*   yTp = (__bf16*)(wsb + ((size_t)16 << 20));  // 4 MB
    __bf16*   wq  = (__bf16*)(wsb + ((size_t)20 << 20));  // 384 KB
    __bf16*   wo  = wq + (size_t)3 * C * C;               // 128 KB

    cvt_kernel<<<256, 256, 0, stream>>>(qkv_w, out_w, wq, wo);
    gn_kernel<<<64, 256, 0, stream>>>(x, gn_w, gn_b, xnT);
    gemm_qkv_kernel<<<dim3(8, 12, 8), 256, 0, stream>>>(wq, xnT, qkv_b,
                                                        Qf, Kf, Vbf);
    attn_kernel<<<1024, 256, 0, stream>>>(Qf, Kf, Vbf, yTp);
    gemm_out_kernel<<<dim3(8, 4, 8), 256, 0, stream>>>(wo, yTp, out_b, out, x);
}

// Round 8
// 126.982 us; speedup vs baseline: 6.6017x; 1.1461x over previous
//
#include <hip/hip_runtime.h>
#include <hip/hip_bf16.h>
#include <math.h>

// ---------------------------------------------------------------------------
// SelfAttention2d: x(8,256,32,32) -> GN(8 groups) -> qkv(768x256 GEMM)
//   -> 32 heads, d=8, attention over t=1024 -> out(256x256 GEMM) + bias + x
// Round 8: (a) attention drops the P lane-exchange by permuting the MFMA
// contraction index (B-frag = S^T C-regs verbatim; V read with the matching
// permuted columns); (b) GroupNorm split into stats(512 blk)+apply(256 blk);
// (c) out-GEMM 64x64 tiles (512 blocks, 2/CU).
// ---------------------------------------------------------------------------

#define NBATCH 8
#define C 256
#define HW 1024
#define NHEAD 32
#define HDIM 8

typedef __bf16 bf16x8 __attribute__((ext_vector_type(8)));
typedef __bf16 bf16x4 __attribute__((ext_vector_type(4)));
typedef _Float16 f16x8 __attribute__((ext_vector_type(8)));
typedef _Float16 f16x4 __attribute__((ext_vector_type(4)));
typedef float floatx4 __attribute__((ext_vector_type(4)));
typedef float floatx16 __attribute__((ext_vector_type(16)));

#if __has_builtin(__builtin_amdgcn_exp2f)
#define EXP2F(x) __builtin_amdgcn_exp2f(x)
#else
#define EXP2F(x) exp2f(x)
#endif

#define SCALE_LOG2E 0.51013249662f   // (1/sqrt(8)) * log2(e)

// -------- weight convert: qkv_w (768x256) + out_w (256x256) fp32 -> bf16 ----
__global__ __launch_bounds__(256) void cvt_kernel(
    const float* __restrict__ qw, const float* __restrict__ ow,
    __bf16* __restrict__ wq, __bf16* __restrict__ wo)
{
    int id = blockIdx.x * 256 + threadIdx.x;     // 0..65535, 4 floats each
    float4 v;
    __bf16* dst;
    if (id < 49152) { v = *(const float4*)&qw[id * 4]; dst = wq + id * 4; }
    else { v = *(const float4*)&ow[(id - 49152) * 4]; dst = wo + (id - 49152) * 4; }
    bf16x4 o = { (__bf16)v.x, (__bf16)v.y, (__bf16)v.z, (__bf16)v.w };
    *(bf16x4*)dst = o;
}

// ---- GN stats: 512 blocks = (n,g,part); part = 4 channels ------------------
__global__ __launch_bounds__(256) void gn_stats_kernel(
    const float* __restrict__ x, float* __restrict__ stats)
{
    int blk = blockIdx.x;
    int part = blk & 7, ng = blk >> 3;
    const float4* xv = (const float4*)(x + ((size_t)ng * 32 + part * 4) * HW);
    int tid = threadIdx.x;
    float s = 0.f, ss = 0.f;
#pragma unroll
    for (int i = 0; i < 4; ++i) {
        float4 v = xv[tid + i * 256];
        s  += v.x + v.y + v.z + v.w;
        ss += v.x*v.x + v.y*v.y + v.z*v.z + v.w*v.w;
    }
#pragma unroll
    for (int o = 32; o; o >>= 1) { s += __shfl_xor(s, o); ss += __shfl_xor(ss, o); }
    __shared__ float rs[4], rss[4];
    int wave = tid >> 6, lane = tid & 63;
    if (lane == 0) { rs[wave] = s; rss[wave] = ss; }
    __syncthreads();
    if (tid == 0) {
        stats[blk * 2]     = rs[0] + rs[1] + rs[2] + rs[3];
        stats[blk * 2 + 1] = rss[0] + rss[1] + rss[2] + rss[3];
    }
}

// ---- GN apply -> xnT bf16 [n][t][c]: 256 blocks = (n,g,chunk of 256 t) -----
__global__ __launch_bounds__(256) void gn_apply_kernel(
    const float* __restrict__ x, const float* __restrict__ w,
    const float* __restrict__ b, const float* __restrict__ stats,
    __bf16* __restrict__ xnT)
{
    int blk = blockIdx.x;
    int chunk = blk & 3, ng = blk >> 2;
    int n = ng >> 3, g = ng & 7;
    float s = 0.f, ss = 0.f;
#pragma unroll
    for (int p = 0; p < 8; ++p) {            // uniform -> scalar loads
        s  += stats[(ng * 8 + p) * 2];
        ss += stats[(ng * 8 + p) * 2 + 1];
    }
    const float invN = 1.0f / 32768.0f;
    float mean = s * invN;
    float var  = ss * invN - mean * mean;
    float rstd = rsqrtf(var + 1e-5f);
    const float* xp = x + ((size_t)ng * 32) * HW;
    int tid = threadIdx.x, t0 = chunk * 256;
    __shared__ __bf16 Lt[32][257];
#pragma unroll 8
    for (int c = 0; c < 32; ++c) {
        float wc = w[g * 32 + c] * rstd;
        float bc = b[g * 32 + c] - mean * wc;
        float v = xp[(size_t)c * HW + t0 + tid];
        Lt[c][tid] = (__bf16)(v * wc + bc);
    }
    __syncthreads();
    __bf16* xo = xnT + (size_t)n * HW * C + g * 32;
#pragma unroll
    for (int q = 0; q < 4; ++q) {
        bf16x8 o;
#pragma unroll
        for (int e = 0; e < 8; ++e) o[e] = Lt[q * 8 + e][tid];
        *(bf16x8*)&xo[(size_t)(t0 + tid) * C + q * 8] = o;
    }
}

// ---- qkv GEMM: 64x128 tile, 4 waves of 32x64; scatter epilogue -------------
// A = qkv_w bf16 [o][c]; B = xnT bf16 [t][c]. Outputs:
//   o<256  -> Qf f16 [n][h][t][8], value*(scale*log2e)
//   o<512  -> Kf f16 [n][h][t][8]
//   else   -> Vb bf16 [n][o-512][t]  (d-major)
__global__ __launch_bounds__(256) void gemm_qkv_kernel(
    const __bf16* __restrict__ W, const __bf16* __restrict__ Ball,
    const float* __restrict__ bias, _Float16* __restrict__ Qf,
    _Float16* __restrict__ Kf, __bf16* __restrict__ Vbf)
{
    int n = blockIdx.z;
    const __bf16* B = Ball + (size_t)n * HW * C;
    int om0 = blockIdx.y * 64, t0 = blockIdx.x * 128;
    __shared__ __bf16 As[64 * 32];
    __shared__ __bf16 Bs[128 * 32];
    int tid = threadIdx.x, lane = tid & 63, wave = tid >> 6;
    int l15 = lane & 15, quad = lane >> 4;
    int wm = (wave & 1) * 32, wn = (wave >> 1) * 64;
    int swq = (quad ^ (l15 & 3)) * 8;
    int arow = tid >> 2, aq = tid & 3;
    int sw = (aq ^ (arow & 3)) * 8;
    floatx4 acc[2][4] = {};
    for (int c0 = 0; c0 < C; c0 += 32) {
        bf16x8 av  = *(const bf16x8*)&W[(size_t)(om0 + arow) * C + c0 + aq * 8];
        bf16x8 bv0 = *(const bf16x8*)&B[(size_t)(t0 + arow) * C + c0 + aq * 8];
        bf16x8 bv1 = *(const bf16x8*)&B[(size_t)(t0 + 64 + arow) * C + c0 + aq * 8];
        __syncthreads();
        *(bf16x8*)&As[arow * 32 + sw] = av;
        *(bf16x8*)&Bs[arow * 32 + sw] = bv0;
        *(bf16x8*)&Bs[(arow + 64) * 32 + sw] = bv1;   // (arow+64)&3 == arow&3
        __syncthreads();
        bf16x8 af[2], bfr[4];
#pragma unroll
        for (int mi = 0; mi < 2; ++mi)
            af[mi] = *(const bf16x8*)&As[(wm + mi * 16 + l15) * 32 + swq];
#pragma unroll
        for (int ni = 0; ni < 4; ++ni)
            bfr[ni] = *(const bf16x8*)&Bs[(wn + ni * 16 + l15) * 32 + swq];
#pragma unroll
        for (int mi = 0; mi < 2; ++mi)
#pragma unroll
            for (int ni = 0; ni < 4; ++ni)
                acc[mi][ni] = __builtin_amdgcn_mfma_f32_16x16x32_bf16(
                    af[mi], bfr[ni], acc[mi][ni], 0, 0, 0);
    }
#pragma unroll
    for (int mi = 0; mi < 2; ++mi) {
        int obase = om0 + wm + mi * 16;         // multiple of 16: Q/K/V uniform
        int oq = obase + quad * 4;              // first of 4 consecutive o
        if (obase < 512) {                      // Q or K: f16x4 [h][t][d0..d0+3]
            int h  = (oq & 255) >> 3;
            int d0 = (quad & 1) * 4;
            _Float16* dst = (obase < 256 ? Qf : Kf);
            float mul = (obase < 256) ? SCALE_LOG2E : 1.0f;
#pragma unroll
            for (int ni = 0; ni < 4; ++ni) {
                int t = t0 + wn + ni * 16 + l15;
                f16x4 o;
#pragma unroll
                for (int r = 0; r < 4; ++r)
                    o[r] = (_Float16)((acc[mi][ni][r] + bias[oq + r]) * mul);
                *(f16x4*)&dst[(((size_t)(n * 32 + h)) * HW + t) * 8 + d0] = o;
            }
        } else {                                // V: bf16 [c][t] scalar stores
            int cv = oq - 512;
#pragma unroll
            for (int ni = 0; ni < 4; ++ni) {
                int t = t0 + wn + ni * 16 + l15;
#pragma unroll
                for (int r = 0; r < 4; ++r)
                    Vbf[((size_t)(n * 256 + cv + r)) * HW + t] =
                        (__bf16)(acc[mi][ni][r] + bias[oq + r]);
            }
        }
    }
}

// ---- out GEMM: 64x64 tile, 4 waves of 32x32; f32 + bias + residual ---------
__global__ __launch_bounds__(256) void gemm_out_kernel(
    const __bf16* __restrict__ W, const __bf16* __restrict__ Ball,
    const float* __restrict__ bias, float* __restrict__ Call,
    const float* __restrict__ Rall)
{
    int n = blockIdx.z;
    const __bf16* B = Ball + (size_t)n * HW * C;
    float* Cp = Call + (size_t)n * C * HW;
    const float* R = Rall + (size_t)n * C * HW;
    int om0 = blockIdx.y * 64, t0 = blockIdx.x * 64;
    __shared__ __bf16 As[64 * 32];
    __shared__ __bf16 Bs[64 * 32];
    int tid = threadIdx.x, lane = tid & 63, wave = tid >> 6;
    int l15 = lane & 15, quad = lane >> 4;
    int wm = (wave & 1) * 32, wn = (wave >> 1) * 32;
    int swq = (quad ^ (l15 & 3)) * 8;
    int arow = tid >> 2, aq = tid & 3;
    int sw = (aq ^ (arow & 3)) * 8;
    floatx4 acc[2][2] = {};
    for (int c0 = 0; c0 < C; c0 += 32) {
        bf16x8 av = *(const bf16x8*)&W[(size_t)(om0 + arow) * C + c0 + aq * 8];
        bf16x8 bv = *(const bf16x8*)&B[(size_t)(t0 + arow) * C + c0 + aq * 8];
        __syncthreads();
        *(bf16x8*)&As[arow * 32 + sw] = av;
        *(bf16x8*)&Bs[arow * 32 + sw] = bv;
        __syncthreads();
        bf16x8 af[2], bfr[2];
#pragma unroll
        for (int mi = 0; mi < 2; ++mi)
            af[mi] = *(const bf16x8*)&As[(wm + mi * 16 + l15) * 32 + swq];
#pragma unroll
        for (int ni = 0; ni < 2; ++ni)
            bfr[ni] = *(const bf16x8*)&Bs[(wn + ni * 16 + l15) * 32 + swq];
#pragma unroll
        for (int mi = 0; mi < 2; ++mi)
#pragma unroll
            for (int ni = 0; ni < 2; ++ni)
                acc[mi][ni] = __builtin_amdgcn_mfma_f32_16x16x32_bf16(
                    af[mi], bfr[ni], acc[mi][ni], 0, 0, 0);
    }
#pragma unroll
    for (int mi = 0; mi < 2; ++mi) {
#pragma unroll
        for (int r = 0; r < 4; ++r) {
            int o = om0 + wm + mi * 16 + quad * 4 + r;
            float bb = bias[o];
#pragma unroll
            for (int ni = 0; ni < 2; ++ni) {
                int t = t0 + wn + ni * 16 + l15;
                Cp[(size_t)o * HW + t] = acc[mi][ni][r] + bb + R[(size_t)o * HW + t];
            }
        }
    }
}

// ---- MFMA attention, permuted-k PV: 1024 blocks = (n,h,quarter) ------------
// S^T = mfma_32x32x16_f16(A=K, B=Q). C-layout: col=tq=l31, row=tk=
// (r&3)+8(r>>2)+4*lhi. PV contracts over a PERMUTED k: slot (lhi,j) ->
// tk=(j&3)+8(j>>2)+4lhi, so B-frag = cvt(S^T regs 0..7 / 8..15) verbatim and
// A-frag = V columns {4lhi, 8+4lhi, 16+4lhi, 24+4lhi} (4x ds_read_b64).
// V rows: 0-7 = V dims, 8 = ones => Y^T row 8 = softmax denom. No exchanges.
__global__ __launch_bounds__(256, 4) void attn_kernel(
    const _Float16* __restrict__ Qf, const _Float16* __restrict__ Kf,
    const __bf16* __restrict__ Vg, __bf16* __restrict__ yT)
{
    int quarter = blockIdx.x & 3, h = (blockIdx.x >> 2) & 31, n = blockIdx.x >> 7;
    __shared__ alignas(16) _Float16 Kb[HW][8];        // 16 KB
    __shared__ alignas(16) __bf16   Vb[9][HW + 8];    // ~18.1 KB, stride 1032
    int tid = threadIdx.x;
    const _Float16* kg = Kf + ((size_t)(n * 32 + h)) * HW * 8;
    const __bf16*   vg = Vg + ((size_t)(n * 256 + h * 8)) * HW;
#pragma unroll
    for (int i = 0; i < 4; ++i) {
        int row = tid + i * 256;
        *(f16x8*)&Kb[row][0] = *(const f16x8*)&kg[(size_t)row * 8];
    }
#pragma unroll
    for (int i = 0; i < 4; ++i) {
        int id = tid + i * 256;
        int d = id >> 7, t8 = (id & 127) * 8;
        *(bf16x8*)&Vb[d][t8] = *(const bf16x8*)&vg[(size_t)d * HW + t8];
    }
    if (tid < 128) {
        __bf16 one = (__bf16)1.0f;
        bf16x8 ones = { one, one, one, one, one, one, one, one };
        *(bf16x8*)&Vb[8][tid * 8] = ones;
    }
    int lane = tid & 63, wave = tid >> 6;
    int l31 = lane & 31, lhi = lane >> 5;
    int vrow = l31 < 9 ? l31 : (l31 & 7);       // rows >8 garbage-tolerant
    const __bf16* vbase = &Vb[vrow][0];
    int tqb = quarter * 256 + wave * 64;
    const _Float16* qg = Qf + ((size_t)(n * 32 + h)) * HW * 8;
    f16x8 qf[2];
#pragma unroll
    for (int tau = 0; tau < 2; ++tau) {
        f16x8 qv = { 0, 0, 0, 0, 0, 0, 0, 0 };
        if (lhi == 0)
            qv = *(const f16x8*)&qg[(size_t)(tqb + tau * 32 + l31) * 8];
        qf[tau] = qv;
    }
    __syncthreads();
    floatx16 accG[2] = {};
    floatx16 zero16 = {};
    for (int tkt = 0; tkt < 32; ++tkt) {
        f16x8 kf = *(const f16x8*)&Kb[tkt * 32 + l31][0];
        int cb = tkt * 32 + lhi * 4;
        bf16x4 va0 = *(const bf16x4*)&vbase[cb];
        bf16x4 va1 = *(const bf16x4*)&vbase[cb + 8];
        bf16x4 va2 = *(const bf16x4*)&vbase[cb + 16];
        bf16x4 va3 = *(const bf16x4*)&vbase[cb + 24];
        bf16x8 vf0 = __builtin_shufflevector(va0, va1, 0, 1, 2, 3, 4, 5, 6, 7);
        bf16x8 vf1 = __builtin_shufflevector(va2, va3, 0, 1, 2, 3, 4, 5, 6, 7);
#pragma unroll
        for (int tau = 0; tau < 2; ++tau) {
            floatx16 sT = __builtin_amdgcn_mfma_f32_32x32x16_f16(
                kf, qf[tau], zero16, 0, 0, 0);
            __bf16 p[16];
#pragma unroll
            for (int r = 0; r < 16; ++r) p[r] = (__bf16)EXP2F(sT[r]);
            bf16x8 P0 = { p[0], p[1], p[2], p[3], p[4], p[5], p[6], p[7] };
            bf16x8 P1 = { p[8], p[9], p[10], p[11], p[12], p[13], p[14], p[15] };
            accG[tau] = __builtin_amdgcn_mfma_f32_32x32x16_bf16(
                vf0, P0, accG[tau], 0, 0, 0);
            accG[tau] = __builtin_amdgcn_mfma_f32_32x32x16_bf16(
                vf1, P1, accG[tau], 0, 0, 0);
        }
    }
    // epilogue: Y^T col=tq=l31; rows: lhi=0 regs0-3 = d0-3, reg4 = denom(row 8);
    // lhi=1 regs0-3 = d4-7. Share denom via lane^32.
    __bf16* yp = yT + (size_t)n * HW * C + h * HDIM + lhi * 4;
#pragma unroll
    for (int tau = 0; tau < 2; ++tau) {
        float own4 = accG[tau][4];
        float part4 = __shfl_xor(own4, 32);
        float lsum = lhi ? part4 : own4;
        float inv = 1.0f / lsum;
        bf16x4 o = { (__bf16)(accG[tau][0] * inv), (__bf16)(accG[tau][1] * inv),
                     (__bf16)(accG[tau][2] * inv), (__bf16)(accG[tau][3] * inv) };
        *(bf16x4*)&yp[(size_t)(tqb + tau * 32 + l31) * C] = o;
    }
}

// ---------------------------------------------------------------------------
extern "C" void kernel_launch(void* const* d_in, const int* in_sizes, int n_in,
                              void* d_out, int out_size, void* d_ws, size_t ws_size,
                              hipStream_t stream)
{
    const float* x     = (const float*)d_in[0];
    const float* gn_w  = (const float*)d_in[1];
    const float* gn_b  = (const float*)d_in[2];
    const float* qkv_w = (const float*)d_in[3];
    const float* qkv_b = (const float*)d_in[4];
    const float* out_w = (const float*)d_in[5];
    const float* out_b = (const float*)d_in[6];
    float* out = (float*)d_out;

    char* wsb = (char*)d_ws;
    __bf16*   xnT = (__bf16*)wsb;                         // 4 MB
    _Float16* Qf  = (_Float16*)(wsb + ((size_t)4 << 20));  // 4 MB
    _Float16* Kf  = (_Float16*)(wsb + ((size_t)8 << 20));  // 4 MB
    __bf16*   Vbf = (__bf16*)(wsb + ((size_t)12 << 20));   // 4 MB
    __bf16*   yTp = (__bf16*)(wsb + ((size_t)16 << 20));   // 4 MB
    __bf16*   wq  = (__bf16*)(wsb + ((size_t)20 << 20));   // 384 KB
    __bf16*   wo  = wq + (size_t)3 * C * C;                // 128 KB
    float*    st  = (float*)(wsb + ((size_t)21 << 20));    // 4 KB stats

    cvt_kernel<<<256, 256, 0, stream>>>(qkv_w, out_w, wq, wo);
    gn_stats_kernel<<<512, 256, 0, stream>>>(x, st);
    gn_apply_kernel<<<256, 256, 0, stream>>>(x, gn_w, gn_b, st, xnT);
    gemm_qkv_kernel<<<dim3(8, 12, 8), 256, 0, stream>>>(wq, xnT, qkv_b,
                                                        Qf, Kf, Vbf);
    attn_kernel<<<1024, 256, 0, stream>>>(Qf, Kf, Vbf, yTp);
    gemm_out_kernel<<<dim3(16, 4, 8), 256, 0, stream>>>(wo, yTp, out_b, out, x);
}